// Round 3
// baseline (24939.096 us; speedup 1.0000x reference)
//
#include <hip/hip_runtime.h>
#include <math.h>
#include <stdint.h>

// ---------------------------------------------------------------------------
// InvertedCognitionModel: B=8, T=2048, D=512, KQ=32, K=4
//   router (fp32 sim + top4, fused) -> gather-mean -> FFN+LN (bf16 MFMA)
//   -> serial gated memory scan (persistent, LDS weights, gu-broadcast,
//      INTRA-XCD L2 tagged exchange with LLC self-healing fallback)
//   -> output GEMV
// ---------------------------------------------------------------------------

using bf16x8 = __attribute__((ext_vector_type(8))) short;
using f32x4v = __attribute__((ext_vector_type(4))) float;
typedef unsigned long long ull;

__device__ inline unsigned short f2b(float f) {
  union { float f; unsigned int u; } v; v.f = f;
  unsigned int r = v.u + 0x7fffu + ((v.u >> 16) & 1u);   // RNE
  return (unsigned short)(r >> 16);
}

__device__ inline float gelu_f(float x) {
  return 0.5f * x * (1.0f + erff(x * 0.70710678118654752f));
}

// ---- L2-tier tagged-word ops (fast path) ----------------------------------
// Plain store: CDNA vL1D is write-through -> the 8B word lands in the XCD's
// shared L2 as one single-copy-atomic transaction. Load with sc0: bypass L1
// only, read the shared L2. Valid ONLY when producer+consumer share an XCD;
// the timeout net below handles every other placement.

__device__ inline void st_l2_u64(ull* p, ull v) {
  asm volatile("global_store_dwordx2 %0, %1, off" :: "v"(p), "v"(v) : "memory");
}

__device__ inline void ld2_l2_u64(const ull* p, ull& a, ull& b) {
  asm volatile("global_load_dwordx2 %0, %2, off sc0\n\t"
               "global_load_dwordx2 %1, %2, off offset:8 sc0\n\t"
               "s_waitcnt vmcnt(0)"
               : "=&v"(a), "=&v"(b) : "v"(p) : "memory");
}

__device__ inline void ld4_l2_u64(const ull* p, ull& a, ull& b, ull& c, ull& d) {
  asm volatile("global_load_dwordx2 %0, %4, off sc0\n\t"
               "global_load_dwordx2 %1, %4, off offset:8 sc0\n\t"
               "global_load_dwordx2 %2, %4, off offset:16 sc0\n\t"
               "global_load_dwordx2 %3, %4, off offset:24 sc0\n\t"
               "s_waitcnt vmcnt(0)"
               : "=&v"(a), "=&v"(b), "=&v"(c), "=&v"(d) : "v"(p) : "memory");
}

// sorted-descending top-4 insert, tie-break lower index first
__device__ inline void ins4(float v, int i,
                            float& v0, int& i0, float& v1, int& i1,
                            float& v2, int& i2, float& v3, int& i3) {
  bool b0 = (v > v0) || (v == v0 && i < i0);
  bool b1 = (v > v1) || (v == v1 && i < i1);
  bool b2 = (v > v2) || (v == v2 && i < i2);
  bool b3 = (v > v3) || (v == v3 && i < i3);
  float nv3 = b2 ? v2 : (b3 ? v : v3); int ni3 = b2 ? i2 : (b3 ? i : i3);
  float nv2 = b1 ? v1 : (b2 ? v : v2); int ni2 = b1 ? i1 : (b2 ? i : i2);
  float nv1 = b0 ? v0 : (b1 ? v : v1); int ni1 = b0 ? i0 : (b1 ? i : i1);
  float nv0 = b0 ? v  : v0;            int ni0 = b0 ? i  : i0;
  v0=nv0; i0=ni0; v1=nv1; i1=ni1; v2=nv2; i2=ni2; v3=nv3; i3=ni3;
}

// ---------------- prep kernels ----------------

__global__ __launch_bounds__(256)
void wqk_kernel(const float* __restrict__ Wq, const float* __restrict__ Wk,
                float* __restrict__ wqk) {
  int id = blockIdx.x * 256 + threadIdx.x;        // < 512*64
  int d = id >> 6, c = id & 63;
  wqk[id] = (c < 32) ? Wq[d * 32 + c] : Wk[d * 32 + (c - 32)];
}

// dst[n][k] = bf16(src[k][n]); src is [>=K x N] row-major, dst [N x K]
__global__ __launch_bounds__(256)
void transpose_bf16_kernel(const float* __restrict__ src,
                           unsigned short* __restrict__ dst, int K, int N) {
  __shared__ float tile[32][33];
  int bk = blockIdx.x << 5, bn = blockIdx.y << 5;
  int c = threadIdx.x & 31, r8 = threadIdx.x >> 5;
  for (int r = r8; r < 32; r += 8) tile[r][c] = src[(size_t)(bk + r) * N + bn + c];
  __syncthreads();
  for (int r = r8; r < 32; r += 8) dst[(size_t)(bn + r) * K + bk + c] = f2b(tile[c][r]);
}

// dst[n][k] = src[k][n] (fp32), for coalesced LDS staging of Wt2 columns
__global__ __launch_bounds__(256)
void transpose_f32_kernel(const float* __restrict__ src,
                          float* __restrict__ dst, int K, int N) {
  __shared__ float tile[32][33];
  int bk = blockIdx.x << 5, bn = blockIdx.y << 5;
  int c = threadIdx.x & 31, r8 = threadIdx.x >> 5;
  for (int r = r8; r < 32; r += 8) tile[r][c] = src[(size_t)(bk + r) * N + bn + c];
  __syncthreads();
  for (int r = r8; r < 32; r += 8) dst[(size_t)(bn + r) * K + bk + c] = tile[c][r];
}

// ---------------- router ----------------

// q|k projection: qkout[b,t,0:32]=q, [32:64]=k (fp32, biases included)
__global__ __launch_bounds__(256)
void qk_kernel(const float* __restrict__ x, const float* __restrict__ wqk,
               const float* __restrict__ bq, const float* __restrict__ bk,
               float* __restrict__ qkout) {
  __shared__ float xs[16][512];
  int tid = threadIdx.x;
  int b = blockIdx.x >> 7;
  int t0 = (blockIdx.x & 127) << 4;
  const float* xb = x + ((size_t)(b * 2048 + t0)) * 512;
#pragma unroll
  for (int i = 0; i < 8; ++i) {
    int f = i * 256 + tid;
    int r = f >> 7, c4 = f & 127;
    *(float4*)&xs[r][c4 * 4] = *(const float4*)&xb[(size_t)r * 512 + c4 * 4];
  }
  __syncthreads();
  int c = tid & 63, r4 = tid >> 6;
  float a0 = 0.f, a1 = 0.f, a2 = 0.f, a3 = 0.f;
#pragma unroll 4
  for (int d = 0; d < 512; ++d) {
    float w = wqk[d * 64 + c];
    a0 += xs[r4][d] * w;
    a1 += xs[r4 + 4][d] * w;
    a2 += xs[r4 + 8][d] * w;
    a3 += xs[r4 + 12][d] * w;
  }
  float bias = (c < 32) ? bq[c] : bk[c - 32];
  size_t base = ((size_t)(b * 2048 + t0)) * 64 + c;
  qkout[base + (size_t)r4 * 64] = a0 + bias;
  qkout[base + (size_t)(r4 + 4) * 64] = a1 + bias;
  qkout[base + (size_t)(r4 + 8) * 64] = a2 + bias;
  qkout[base + (size_t)(r4 + 12) * 64] = a3 + bias;
}

// fused sim + top-4: block = 16 query rows; never materializes sim
__global__ __launch_bounds__(256)
void topk_kernel(const float* __restrict__ qkb, int* __restrict__ idxout) {
  __shared__ float qs[16][36];
  __shared__ float ks[128][36];
  __shared__ float mv[16][16][4];
  __shared__ int   mi[16][16][4];
  int tid = threadIdx.x;
  int b = blockIdx.x >> 7;
  int t0 = (blockIdx.x & 127) << 4;
  const float* qb = qkb + ((size_t)b * 2048) * 64;
  if (tid < 128) {
    int r = tid >> 3, c4 = tid & 7;
    *(float4*)&qs[r][c4 * 4] = *(const float4*)&qb[(size_t)(t0 + r) * 64 + c4 * 4];
  }
  __syncthreads();
  int tl = tid >> 4, sl = tid & 15;
  float qv[32];
#pragma unroll
  for (int kk = 0; kk < 32; ++kk) qv[kk] = qs[tl][kk];
  float v0 = -INFINITY, v1 = -INFINITY, v2 = -INFINITY, v3 = -INFINITY;
  int i0 = 0x7fffffff, i1 = 0x7fffffff, i2 = 0x7fffffff, i3 = 0x7fffffff;
  for (int s0 = 0; s0 < 2048; s0 += 128) {
    __syncthreads();
#pragma unroll
    for (int p = 0; p < 4; ++p) {
      int f = p * 256 + tid;
      int r = f >> 3, c4 = f & 7;
      *(float4*)&ks[r][c4 * 4] =
          *(const float4*)&qb[(size_t)(s0 + r) * 64 + 32 + c4 * 4];
    }
    __syncthreads();
#pragma unroll
    for (int j = 0; j < 8; ++j) {
      int srow = j * 16 + sl;
      float accv = 0.f;
#pragma unroll
      for (int k4 = 0; k4 < 8; ++k4) {
        float4 kv = *(const float4*)&ks[srow][k4 * 4];
        accv += qv[k4 * 4 + 0] * kv.x + qv[k4 * 4 + 1] * kv.y +
                qv[k4 * 4 + 2] * kv.z + qv[k4 * 4 + 3] * kv.w;
      }
      ins4(accv, s0 + srow, v0, i0, v1, i1, v2, i2, v3, i3);
    }
  }
  mv[tl][sl][0] = v0; mv[tl][sl][1] = v1; mv[tl][sl][2] = v2; mv[tl][sl][3] = v3;
  mi[tl][sl][0] = i0; mi[tl][sl][1] = i1; mi[tl][sl][2] = i2; mi[tl][sl][3] = i3;
  __syncthreads();
  if (tid < 16) {
    float w0 = -INFINITY, w1 = -INFINITY, w2 = -INFINITY, w3 = -INFINITY;
    int a0 = 0x7fffffff, a1 = 0x7fffffff, a2 = 0x7fffffff, a3 = 0x7fffffff;
    for (int ss = 0; ss < 16; ++ss)
#pragma unroll
      for (int q = 0; q < 4; ++q)
        ins4(mv[tid][ss][q], mi[tid][ss][q], w0, a0, w1, a1, w2, a2, w3, a3);
    int4 o; o.x = a0; o.y = a1; o.z = a2; o.w = a3;
    *(int4*)&idxout[((size_t)(b * 2048 + t0 + tid)) * 4] = o;
  }
}

__global__ __launch_bounds__(128)
void gather_kernel(const float* __restrict__ x, const int* __restrict__ idx,
                   float* __restrict__ gf, unsigned short* __restrict__ gb) {
  int bt = blockIdx.x;
  int b = bt >> 11;
  const int4 iv = *(const int4*)&idx[(size_t)bt * 4];
  int tid = threadIdx.x;
  const float* xb = x + ((size_t)b * 2048) * 512;
  float4 p0 = *(const float4*)&xb[(size_t)iv.x * 512 + tid * 4];
  float4 p1 = *(const float4*)&xb[(size_t)iv.y * 512 + tid * 4];
  float4 p2 = *(const float4*)&xb[(size_t)iv.z * 512 + tid * 4];
  float4 p3 = *(const float4*)&xb[(size_t)iv.w * 512 + tid * 4];
  float4 m;
  m.x = (p0.x + p1.x + p2.x + p3.x) * 0.25f;
  m.y = (p0.y + p1.y + p2.y + p3.y) * 0.25f;
  m.z = (p0.z + p1.z + p2.z + p3.z) * 0.25f;
  m.w = (p0.w + p1.w + p2.w + p3.w) * 0.25f;
  *(float4*)&gf[(size_t)bt * 512 + tid * 4] = m;
  ushort4 u; u.x = f2b(m.x); u.y = f2b(m.y); u.z = f2b(m.z); u.w = f2b(m.w);
  *(ushort4*)&gb[(size_t)bt * 512 + tid * 4] = u;
}

// ---------------- MFMA GEMM: C = A[MxK] * Bt[NxK]^T (+bias, epilogues) ------
// MODE 0: out bf16 = gelu(acc+bias)   MODE 1: out f32 = acc+bias+resid
// MODE 2: out f32 = acc+bias

template <int MODE>
__global__ __launch_bounds__(256, 2)
void gemm_bf16_k(const unsigned short* __restrict__ A,
                 const unsigned short* __restrict__ Bt,
                 const float* __restrict__ bias,
                 const float* __restrict__ resid,
                 void* __restrict__ outp, int M, int N, int K) {
  __shared__ unsigned short sA[128 * 32];
  __shared__ unsigned short sB[128 * 32];
  const int tid = threadIdx.x;
  const int lane = tid & 63, wave = tid >> 6;
  const int m0 = blockIdx.x * 128, n0 = blockIdx.y * 128;
  const int col16 = lane & 15, quad = lane >> 4;
  const int wm = wave >> 1, wn = wave & 1;
  f32x4v acc[4][4];
#pragma unroll
  for (int i = 0; i < 4; ++i)
#pragma unroll
    for (int j = 0; j < 4; ++j) {
      f32x4v z = {0.f, 0.f, 0.f, 0.f};
      acc[i][j] = z;
    }
  const int nkt = K >> 5;
  for (int kt = 0; kt < nkt; ++kt) {
    const int k0 = kt << 5;
#pragma unroll
    for (int p = 0; p < 2; ++p) {
      int f = p * 256 + tid;
      int row = f >> 2, q4 = f & 3;
      *(uint4*)&sA[row * 32 + q4 * 8] =
          *(const uint4*)(A + (size_t)(m0 + row) * K + k0 + q4 * 8);
      *(uint4*)&sB[row * 32 + q4 * 8] =
          *(const uint4*)(Bt + (size_t)(n0 + row) * K + k0 + q4 * 8);
    }
    __syncthreads();
    bf16x8 af[4], bfr[4];
#pragma unroll
    for (int i = 0; i < 4; ++i)
      af[i] = *(const bf16x8*)&sA[(wm * 64 + i * 16 + col16) * 32 + quad * 8];
#pragma unroll
    for (int j = 0; j < 4; ++j)
      bfr[j] = *(const bf16x8*)&sB[(wn * 64 + j * 16 + col16) * 32 + quad * 8];
#pragma unroll
    for (int i = 0; i < 4; ++i)
#pragma unroll
      for (int j = 0; j < 4; ++j)
        acc[i][j] = __builtin_amdgcn_mfma_f32_16x16x32_bf16(af[i], bfr[j],
                                                            acc[i][j], 0, 0, 0);
    __syncthreads();
  }
  float* outf = (float*)outp;
  unsigned short* outb = (unsigned short*)outp;
#pragma unroll
  for (int i = 0; i < 4; ++i)
#pragma unroll
    for (int j = 0; j < 4; ++j) {
      int col = n0 + wn * 64 + j * 16 + col16;
      float bs = bias[col];
#pragma unroll
      for (int r = 0; r < 4; ++r) {
        int row = m0 + wm * 64 + i * 16 + quad * 4 + r;
        float v = acc[i][j][r] + bs;
        if (MODE == 0) {
          outb[(size_t)row * N + col] = f2b(gelu_f(v));
        } else if (MODE == 1) {
          outf[(size_t)row * N + col] = v + resid[(size_t)row * N + col];
        } else {
          outf[(size_t)row * N + col] = v;
        }
      }
    }
}

// ---------------- LayerNorm (row-wise, fp32 -> bf16) ----------------

__global__ __launch_bounds__(128)
void ln_kernel(const float* __restrict__ ypre, const float* __restrict__ lg,
               const float* __restrict__ lb, unsigned short* __restrict__ yb) {
  int row = blockIdx.x, tid = threadIdx.x;
  float4 v = *(const float4*)&ypre[(size_t)row * 512 + tid * 4];
  float s = v.x + v.y + v.z + v.w;
  float sq = v.x * v.x + v.y * v.y + v.z * v.z + v.w * v.w;
#pragma unroll
  for (int off = 1; off < 64; off <<= 1) {
    s += __shfl_xor(s, off, 64);
    sq += __shfl_xor(sq, off, 64);
  }
  __shared__ float red[4];
  if ((tid & 63) == 0) { red[(tid >> 6) * 2] = s; red[(tid >> 6) * 2 + 1] = sq; }
  __syncthreads();
  float S = red[0] + red[2], SQ = red[1] + red[3];
  float mu = S * (1.f / 512.f);
  float var = SQ * (1.f / 512.f) - mu * mu;
  float rstd = rsqrtf(var + 1e-5f);
  float4 g4 = *(const float4*)&lg[tid * 4];
  float4 b4 = *(const float4*)&lb[tid * 4];
  ushort4 u;
  u.x = f2b((v.x - mu) * rstd * g4.x + b4.x);
  u.y = f2b((v.y - mu) * rstd * g4.y + b4.y);
  u.z = f2b((v.z - mu) * rstd * g4.z + b4.z);
  u.w = f2b((v.w - mu) * rstd * g4.w + b4.w);
  *(ushort4*)&yb[(size_t)row * 512 + tid * 4] = u;
}

// ---------------- System2: persistent serial scan --------------------------
// 8 teams x 32 WGs x 256 thr; blockIdx = g*8 + team.
// WG g owns u-cols [g*32,g*32+32) and mem-cols [g*16,g*16+16).
//
// STRUCTURE (gu-broadcast, R2): WG g computes its 32 gu values from full
// mem, broadcasts them (1024 words/team round A); holds Wt2 columns for its
// 16 mem-cols and computes full prop from full gu; broadcasts its 16 mem
// values (512 words/team round B). Tagged words: (tag<<32)|float_bits,
// tag = s+1, parity double-buffer. Monotone tags: stale content is either
// 0xAAAAAAAA poison or >=2047 (prev launch final) vs expected tags counting
// up from 1 -> no false match. 8B aligned stores/loads are single-copy
// atomic, so the tag travels with the payload: no flags, no drains.
//
// TIER v4 (this round): teams map to blockIdx%8 -> under round-robin
// dispatch all 32 WGs of a team share ONE XCD and its 4MiB L2 (~250cy)
// instead of the LLC (~900cy). Fast path: plain write-through stores +
// sc0 (L1-bypass) poll loads = the whole exchange lives in the shared L2.
// Since WG->XCD placement is formally undefined (G16), every thread has a
// TIMEOUT NET: after 3000 failed poll iterations it permanently switches
// to the proven agent-scope/LLC protocol and republishes the words it owns
// (retained last-written values, both parities) via LLC. Broken placement
// stalls at step 0-1 (stale tags can't match low tags), every WG times out
// once, and the team converges to the R2-speed slow path -- correct, just
// slow. Mixed mode is safe: sc1 stores write THROUGH L2 (update local line
// + LLC); sc0 loads that miss L2 fall through to the LLC.

__global__ __launch_bounds__(256)
void system2_kernel(const float* __restrict__ Wt1, const float* __restrict__ Wt2T,
                    const float* __restrict__ bt2, const float* __restrict__ xpart,
                    ull* __restrict__ guT, ull* __restrict__ memT,
                    float* __restrict__ memfinal) {
  __shared__ float WbT[32 * 516];    // stage1 W [j][k], stride 516 (66048 B)
  __shared__ float W2S[16 * 1028];   // stage2 W [dd][u], stride 1028 (65792 B)
  __shared__ float memS[512];
  __shared__ float guA[1024];
  __shared__ float parts1[256];      // [c][j] = [8][32]
  __shared__ float red2[256];        // [c2][dd] = [16][16]

  const int t = threadIdx.x;
  const int team = blockIdx.x & 7;
  const int g = blockIdx.x >> 3;          // 0..31
  const int ucol0 = g << 5;
  const int mcol0 = g << 4;

  // ---- load weights into LDS (one-time) ----
  for (int idx = t; idx < 32 * 512; idx += 256) {
    int j = idx & 31, k = idx >> 5;
    WbT[j * 516 + k] = Wt1[(size_t)(512 + k) * 1024 + ucol0 + j];
  }
  for (int idx = t; idx < 16 * 1024; idx += 256) {
    int dd = idx >> 10, u = idx & 1023;
    W2S[dd * 1028 + u] = Wt2T[(size_t)(mcol0 + dd) * 1024 + u];
  }
  memS[t] = 0.f;
  memS[t + 256] = 0.f;
  const float bt2r = (t < 16) ? bt2[mcol0 + t] : 0.f;
  __syncthreads();

  const int j = t & 31, c = t >> 5;        // stage1 roles: col j, k-chunk c(8)
  const int dd = t & 15, c2 = t >> 4;      // stage2 roles: col dd, u-chunk c2(16)
  const float* xp = xpart + (size_t)team * 2048 * 1024 + ucol0;
  float xv = (t < 32) ? xp[t] : 0.f;

  // sticky per-thread fallback state + retained last-written words
  int slowR = 0;
  ull guW0 = 0, guW1 = 0, memW0 = 0, memW1 = 0;
  const int TIMEOUT = 3000;

  auto republish = [&]() {
    // re-store everything this thread owns, both parities, via LLC
    if (t < 32) {
      __hip_atomic_store(guT + (size_t)(0 * 8 + team) * 1024 + ucol0 + t, guW0,
                         __ATOMIC_RELAXED, __HIP_MEMORY_SCOPE_AGENT);
      __hip_atomic_store(guT + (size_t)(1 * 8 + team) * 1024 + ucol0 + t, guW1,
                         __ATOMIC_RELAXED, __HIP_MEMORY_SCOPE_AGENT);
    }
    if (t < 16) {
      __hip_atomic_store(memT + (size_t)(0 * 8 + team) * 512 + mcol0 + t, memW0,
                         __ATOMIC_RELAXED, __HIP_MEMORY_SCOPE_AGENT);
      __hip_atomic_store(memT + (size_t)(1 * 8 + team) * 512 + mcol0 + t, memW1,
                         __ATOMIC_RELAXED, __HIP_MEMORY_SCOPE_AGENT);
    }
  };

  for (int s = 0; s < 2048; ++s) {
    const int par = s & 1;
    ull* gub = guT + (size_t)(par * 8 + team) * 1024;
    ull* memb = memT + (size_t)(par * 8 + team) * 512;
    const unsigned utag = (unsigned)(s + 1);
    const ull tagw = ((ull)utag) << 32;

    // ---- stage1: u[ucol0+j] partial over k-chunk c (64 k), float4 LDS ----
    {
      const float* wrow = &WbT[j * 516 + c * 64];
      const float* mrow = &memS[c * 64];
      float p1 = 0.f;
#pragma unroll
      for (int i = 0; i < 64; i += 4) {
        float4 wv = *(const float4*)&wrow[i];
        float4 mv = *(const float4*)&mrow[i];
        p1 += wv.x * mv.x + wv.y * mv.y + wv.z * mv.z + wv.w * mv.w;
      }
      parts1[c * 32 + j] = p1;
    }
    __syncthreads();
    // ---- own 32 gu values: reduce, gelu, tagged broadcast store ----
    if (t < 32) {
      float u = xv;   // xpart includes xt@Wt1[:512] + bt1
#pragma unroll
      for (int cc = 0; cc < 8; ++cc) u += parts1[cc * 32 + t];
      float gv = gelu_f(u);
      union { float f; unsigned u; } uv; uv.f = gv;
      ull w = tagw | uv.u;
      if (par) guW1 = w; else guW0 = w;
      if (slowR)
        __hip_atomic_store(&gub[ucol0 + t], w, __ATOMIC_RELAXED,
                           __HIP_MEMORY_SCOPE_AGENT);
      else
        st_l2_u64(&gub[ucol0 + t], w);
    }
    asm volatile("" ::: "memory");  // compiler-only: stores before polls

    // ---- poll full gu (4 tagged words per thread) -> guA ----
    {
      ull* p = &gub[t * 4];
      ull v0, v1, v2, v3;
      int it = 0;
      for (;;) {
        if (slowR) {
          v0 = __hip_atomic_load(&p[0], __ATOMIC_RELAXED, __HIP_MEMORY_SCOPE_AGENT);
          v1 = __hip_atomic_load(&p[1], __ATOMIC_RELAXED, __HIP_MEMORY_SCOPE_AGENT);
          v2 = __hip_atomic_load(&p[2], __ATOMIC_RELAXED, __HIP_MEMORY_SCOPE_AGENT);
          v3 = __hip_atomic_load(&p[3], __ATOMIC_RELAXED, __HIP_MEMORY_SCOPE_AGENT);
        } else {
          ld4_l2_u64(p, v0, v1, v2, v3);
        }
        bool ok = ((unsigned)(v0 >> 32) == utag) & ((unsigned)(v1 >> 32) == utag) &
                  ((unsigned)(v2 >> 32) == utag) & ((unsigned)(v3 >> 32) == utag);
        if (ok) break;
        if (++it == TIMEOUT) { slowR = 1; republish(); }
        __builtin_amdgcn_s_sleep(1);
      }
      union { unsigned u; float f; } a0, a1, a2, a3;
      a0.u = (unsigned)v0; a1.u = (unsigned)v1;
      a2.u = (unsigned)v2; a3.u = (unsigned)v3;
      guA[t * 4 + 0] = a0.f;
      guA[t * 4 + 1] = a1.f;
      guA[t * 4 + 2] = a2.f;
      guA[t * 4 + 3] = a3.f;
    }
    // xpart prefetch HERE (not before poll-A): keeps its ~900cy HBM latency
    // out of the first poll iteration's vmcnt(0); hidden under stage2+roundB.
    float xnext = (t < 32 && s < 2047) ? xp[(size_t)(s + 1) * 1024 + t] : 0.f;
    __syncthreads();

    // ---- stage2: full prop for own col (mcol0+dd), u-chunk c2 (64 u) ----
    {
      const float* wrow = &W2S[dd * 1028 + c2 * 64];
      const float* grow = &guA[c2 * 64];
      float p2 = 0.f;
#pragma unroll
      for (int i = 0; i < 64; i += 4) {
        float4 wv = *(const float4*)&wrow[i];
        float4 gv = *(const float4*)&grow[i];
        p2 += wv.x * gv.x + wv.y * gv.y + wv.z * gv.z + wv.w * gv.w;
      }
      red2[c2 * 16 + dd] = p2;
    }
    __syncthreads();
    // ---- own 16 mem-cols: reduce 16 chunks, gate, tagged mem store ----
    if (t < 16) {
      float prop = bt2r;
#pragma unroll
      for (int cc = 0; cc < 16; ++cc) prop += red2[cc * 16 + t];
      float gate = 1.f / (1.f + __expf(-prop));
      float mnew = memS[mcol0 + t] * (1.f - gate) + prop * gate;
      union { float f; unsigned u; } mv; mv.f = mnew;
      ull w = tagw | mv.u;
      if (par) memW1 = w; else memW0 = w;
      if (slowR)
        __hip_atomic_store(&memb[mcol0 + t], w, __ATOMIC_RELAXED,
                           __HIP_MEMORY_SCOPE_AGENT);
      else
        st_l2_u64(&memb[mcol0 + t], w);
    }
    asm volatile("" ::: "memory");

    // ---- poll full mem (2 tagged words per thread) -> memS ----
    {
      ull* q = &memb[t * 2];
      ull v1, v2;
      int it = 0;
      for (;;) {
        if (slowR) {
          v1 = __hip_atomic_load(&q[0], __ATOMIC_RELAXED, __HIP_MEMORY_SCOPE_AGENT);
          v2 = __hip_atomic_load(&q[1], __ATOMIC_RELAXED, __HIP_MEMORY_SCOPE_AGENT);
        } else {
          ld2_l2_u64(q, v1, v2);
        }
        if (((unsigned)(v1 >> 32) == utag) & ((unsigned)(v2 >> 32) == utag)) break;
        if (++it == TIMEOUT) { slowR = 1; republish(); }
        __builtin_amdgcn_s_sleep(1);
      }
      union { unsigned u; float f; } m1, m2;
      m1.u = (unsigned)v1; m2.u = (unsigned)v2;
      memS[t * 2] = m1.f;
      memS[t * 2 + 1] = m2.f;
    }
    xv = xnext;
    __syncthreads();
  }

  if (g == 0 && t < 128)
    *(float4*)&memfinal[(size_t)team * 512 + t * 4] = *(float4*)&memS[t * 4];
}

// ---------------- output GEMV ----------------

__global__ __launch_bounds__(256)
void out_gemv_kernel(const float* __restrict__ memf, const float* __restrict__ Wo,
                     const float* __restrict__ bo, float* __restrict__ out) {
  int gid = blockIdx.x * 256 + threadIdx.x;   // 4096 total
  int b = gid >> 9, d = gid & 511;
  const float* mb = memf + (size_t)b * 512;
  float acc = bo[d];
#pragma unroll 8
  for (int k = 0; k < 512; ++k) acc += mb[k] * Wo[(size_t)k * 512 + d];
  out[gid] = acc;
}

// ---------------- launch ----------------

extern "C" void kernel_launch(void* const* d_in, const int* in_sizes, int n_in,
                              void* d_out, int out_size, void* d_ws, size_t ws_size,
                              hipStream_t stream) {
  const float* x   = (const float*)d_in[0];
  const float* Wq  = (const float*)d_in[1];
  const float* bq  = (const float*)d_in[2];
  const float* Wk  = (const float*)d_in[3];
  const float* bk  = (const float*)d_in[4];
  const float* W1  = (const float*)d_in[5];
  const float* b1  = (const float*)d_in[6];
  const float* W2  = (const float*)d_in[7];
  const float* b2  = (const float*)d_in[8];
  const float* lng = (const float*)d_in[9];
  const float* lnb = (const float*)d_in[10];
  const float* Wt1 = (const float*)d_in[11];
  const float* bt1 = (const float*)d_in[12];
  const float* Wt2 = (const float*)d_in[13];
  const float* bt2 = (const float*)d_in[14];
  const float* Wo  = (const float*)d_in[15];
  const float* bo  = (const float*)d_in[16];
  float* out = (float*)d_out;

  char* ws = (char*)d_ws;
  size_t off = 0;
  auto alloc = [&](size_t bytes) -> void* {
    void* p = ws + off;
    off += (bytes + 255) & ~(size_t)255;
    return p;
  };
  float* qk             = (float*)alloc(8ull * 2048 * 64 * 4);
  int* idxb             = (int*)alloc(8ull * 2048 * 4 * 4);
  float* gathf          = (float*)alloc(16384ull * 512 * 4);
  unsigned short* gathb = (unsigned short*)alloc(16384ull * 512 * 2);
  unsigned short* h1b   = (unsigned short*)alloc(16384ull * 1024 * 2);
  float* ypre           = (float*)alloc(16384ull * 512 * 4);
  unsigned short* yb    = (unsigned short*)alloc(16384ull * 512 * 2);
  float* xpart          = (float*)alloc(16384ull * 1024 * 4);
  unsigned short* w1t   = (unsigned short*)alloc(1024ull * 512 * 2);
  unsigned short* w2t   = (unsigned short*)alloc(512ull * 1024 * 2);
  unsigned short* wt1t  = (unsigned short*)alloc(1024ull * 512 * 2);
  float* wt2t           = (float*)alloc(512ull * 1024 * 4);      // Wt2^T fp32
  float* wqkb           = (float*)alloc(512ull * 64 * 4);
  ull* guT              = (ull*)alloc(2ull * 8 * 1024 * 8);      // 128 KB
  ull* memT             = (ull*)alloc(2ull * 8 * 512 * 8);       // 64 KB
  float* memf           = (float*)alloc(8ull * 512 * 4);
  if (off > ws_size) return;  // workspace too small -> visible bench failure

  wqk_kernel<<<128, 256, 0, stream>>>(Wq, Wk, wqkb);
  transpose_bf16_kernel<<<dim3(16, 32), 256, 0, stream>>>(W1, w1t, 512, 1024);
  transpose_bf16_kernel<<<dim3(32, 16), 256, 0, stream>>>(W2, w2t, 1024, 512);
  transpose_bf16_kernel<<<dim3(16, 32), 256, 0, stream>>>(Wt1, wt1t, 512, 1024);
  transpose_f32_kernel<<<dim3(32, 16), 256, 0, stream>>>(Wt2, wt2t, 1024, 512);

  qk_kernel<<<1024, 256, 0, stream>>>(x, wqkb, bq, bk, qk);
  topk_kernel<<<1024, 256, 0, stream>>>(qk, idxb);
  gather_kernel<<<16384, 128, 0, stream>>>(x, idxb, gathf, gathb);

  gemm_bf16_k<0><<<dim3(128, 8), 256, 0, stream>>>(gathb, w1t, b1, nullptr, h1b,
                                                   16384, 1024, 512);
  gemm_bf16_k<1><<<dim3(128, 4), 256, 0, stream>>>(h1b, w2t, b2, gathf, ypre,
                                                   16384, 512, 1024);
  ln_kernel<<<16384, 128, 0, stream>>>(ypre, lng, lnb, yb);
  gemm_bf16_k<2><<<dim3(128, 8), 256, 0, stream>>>(yb, wt1t, bt1, nullptr, xpart,
                                                   16384, 1024, 512);

  system2_kernel<<<256, 256, 0, stream>>>(Wt1, wt2t, bt2, xpart, guT, memT,
                                          memf);
  out_gemv_kernel<<<16, 256, 0, stream>>>(memf, Wo, bo, out);
}

// Round 4
// 11772.531 us; speedup vs baseline: 2.1184x; 2.1184x over previous
//
#include <hip/hip_runtime.h>
#include <math.h>
#include <stdint.h>

// ---------------------------------------------------------------------------
// InvertedCognitionModel: B=8, T=2048, D=512, KQ=32, K=4
//   router (fp32 sim + top4, fused) -> gather-mean -> FFN+LN (bf16 MFMA)
//   -> serial gated memory scan (persistent, LDS weights, gu-broadcast,
//      XCC_ID-verified intra-XCD L2 exchange; LLC tier for impure teams)
//   -> output GEMV
// ---------------------------------------------------------------------------

using bf16x8 = __attribute__((ext_vector_type(8))) short;
using f32x4v = __attribute__((ext_vector_type(4))) float;
typedef unsigned long long ull;

__device__ inline unsigned short f2b(float f) {
  union { float f; unsigned int u; } v; v.f = f;
  unsigned int r = v.u + 0x7fffu + ((v.u >> 16) & 1u);   // RNE
  return (unsigned short)(r >> 16);
}

__device__ inline float gelu_f(float x) {
  return 0.5f * x * (1.0f + erff(x * 0.70710678118654752f));
}

// ---- L2-tier tagged-word ops (fast path; valid only for co-XCD teams) -----
// Plain store: CDNA vL1D is write-through -> the 8B word lands in the XCD's
// shared L2 as one single-copy-atomic transaction. Load with sc0: bypass L1
// only, read the shared L2.

__device__ inline void st_l2_u64(ull* p, ull v) {
  asm volatile("global_store_dwordx2 %0, %1, off" :: "v"(p), "v"(v) : "memory");
}

__device__ inline void ld2_l2_u64(const ull* p, ull& a, ull& b) {
  asm volatile("global_load_dwordx2 %0, %2, off sc0\n\t"
               "global_load_dwordx2 %1, %2, off offset:8 sc0\n\t"
               "s_waitcnt vmcnt(0)"
               : "=&v"(a), "=&v"(b) : "v"(p) : "memory");
}

__device__ inline void ld4_l2_u64(const ull* p, ull& a, ull& b, ull& c, ull& d) {
  asm volatile("global_load_dwordx2 %0, %4, off sc0\n\t"
               "global_load_dwordx2 %1, %4, off offset:8 sc0\n\t"
               "global_load_dwordx2 %2, %4, off offset:16 sc0\n\t"
               "global_load_dwordx2 %3, %4, off offset:24 sc0\n\t"
               "s_waitcnt vmcnt(0)"
               : "=&v"(a), "=&v"(b), "=&v"(c), "=&v"(d) : "v"(p) : "memory");
}

// sorted-descending top-4 insert, tie-break lower index first
__device__ inline void ins4(float v, int i,
                            float& v0, int& i0, float& v1, int& i1,
                            float& v2, int& i2, float& v3, int& i3) {
  bool b0 = (v > v0) || (v == v0 && i < i0);
  bool b1 = (v > v1) || (v == v1 && i < i1);
  bool b2 = (v > v2) || (v == v2 && i < i2);
  bool b3 = (v > v3) || (v == v3 && i < i3);
  float nv3 = b2 ? v2 : (b3 ? v : v3); int ni3 = b2 ? i2 : (b3 ? i : i3);
  float nv2 = b1 ? v1 : (b2 ? v : v2); int ni2 = b1 ? i1 : (b2 ? i : i2);
  float nv1 = b0 ? v0 : (b1 ? v : v1); int ni1 = b0 ? i0 : (b1 ? i : i1);
  float nv0 = b0 ? v  : v0;            int ni0 = b0 ? i  : i0;
  v0=nv0; i0=ni0; v1=nv1; i1=ni1; v2=nv2; i2=ni2; v3=nv3; i3=ni3;
}

// ---------------- prep kernels ----------------

__global__ __launch_bounds__(64)
void zero_kernel(int* __restrict__ p) {
  p[threadIdx.x] = 0;
}

__global__ __launch_bounds__(256)
void wqk_kernel(const float* __restrict__ Wq, const float* __restrict__ Wk,
                float* __restrict__ wqk) {
  int id = blockIdx.x * 256 + threadIdx.x;        // < 512*64
  int d = id >> 6, c = id & 63;
  wqk[id] = (c < 32) ? Wq[d * 32 + c] : Wk[d * 32 + (c - 32)];
}

// dst[n][k] = bf16(src[k][n]); src is [>=K x N] row-major, dst [N x K]
__global__ __launch_bounds__(256)
void transpose_bf16_kernel(const float* __restrict__ src,
                           unsigned short* __restrict__ dst, int K, int N) {
  __shared__ float tile[32][33];
  int bk = blockIdx.x << 5, bn = blockIdx.y << 5;
  int c = threadIdx.x & 31, r8 = threadIdx.x >> 5;
  for (int r = r8; r < 32; r += 8) tile[r][c] = src[(size_t)(bk + r) * N + bn + c];
  __syncthreads();
  for (int r = r8; r < 32; r += 8) dst[(size_t)(bn + r) * K + bk + c] = f2b(tile[c][r]);
}

// dst[n][k] = src[k][n] (fp32), for coalesced LDS staging of Wt2 columns
__global__ __launch_bounds__(256)
void transpose_f32_kernel(const float* __restrict__ src,
                          float* __restrict__ dst, int K, int N) {
  __shared__ float tile[32][33];
  int bk = blockIdx.x << 5, bn = blockIdx.y << 5;
  int c = threadIdx.x & 31, r8 = threadIdx.x >> 5;
  for (int r = r8; r < 32; r += 8) tile[r][c] = src[(size_t)(bk + r) * N + bn + c];
  __syncthreads();
  for (int r = r8; r < 32; r += 8) dst[(size_t)(bn + r) * K + bk + c] = tile[c][r];
}

// ---------------- router ----------------

// q|k projection: qkout[b,t,0:32]=q, [32:64]=k (fp32, biases included)
__global__ __launch_bounds__(256)
void qk_kernel(const float* __restrict__ x, const float* __restrict__ wqk,
               const float* __restrict__ bq, const float* __restrict__ bk,
               float* __restrict__ qkout) {
  __shared__ float xs[16][512];
  int tid = threadIdx.x;
  int b = blockIdx.x >> 7;
  int t0 = (blockIdx.x & 127) << 4;
  const float* xb = x + ((size_t)(b * 2048 + t0)) * 512;
#pragma unroll
  for (int i = 0; i < 8; ++i) {
    int f = i * 256 + tid;
    int r = f >> 7, c4 = f & 127;
    *(float4*)&xs[r][c4 * 4] = *(const float4*)&xb[(size_t)r * 512 + c4 * 4];
  }
  __syncthreads();
  int c = tid & 63, r4 = tid >> 6;
  float a0 = 0.f, a1 = 0.f, a2 = 0.f, a3 = 0.f;
#pragma unroll 4
  for (int d = 0; d < 512; ++d) {
    float w = wqk[d * 64 + c];
    a0 += xs[r4][d] * w;
    a1 += xs[r4 + 4][d] * w;
    a2 += xs[r4 + 8][d] * w;
    a3 += xs[r4 + 12][d] * w;
  }
  float bias = (c < 32) ? bq[c] : bk[c - 32];
  size_t base = ((size_t)(b * 2048 + t0)) * 64 + c;
  qkout[base + (size_t)r4 * 64] = a0 + bias;
  qkout[base + (size_t)(r4 + 4) * 64] = a1 + bias;
  qkout[base + (size_t)(r4 + 8) * 64] = a2 + bias;
  qkout[base + (size_t)(r4 + 12) * 64] = a3 + bias;
}

// fused sim + top-4: block = 16 query rows; never materializes sim
__global__ __launch_bounds__(256)
void topk_kernel(const float* __restrict__ qkb, int* __restrict__ idxout) {
  __shared__ float qs[16][36];
  __shared__ float ks[128][36];
  __shared__ float mv[16][16][4];
  __shared__ int   mi[16][16][4];
  int tid = threadIdx.x;
  int b = blockIdx.x >> 7;
  int t0 = (blockIdx.x & 127) << 4;
  const float* qb = qkb + ((size_t)b * 2048) * 64;
  if (tid < 128) {
    int r = tid >> 3, c4 = tid & 7;
    *(float4*)&qs[r][c4 * 4] = *(const float4*)&qb[(size_t)(t0 + r) * 64 + c4 * 4];
  }
  __syncthreads();
  int tl = tid >> 4, sl = tid & 15;
  float qv[32];
#pragma unroll
  for (int kk = 0; kk < 32; ++kk) qv[kk] = qs[tl][kk];
  float v0 = -INFINITY, v1 = -INFINITY, v2 = -INFINITY, v3 = -INFINITY;
  int i0 = 0x7fffffff, i1 = 0x7fffffff, i2 = 0x7fffffff, i3 = 0x7fffffff;
  for (int s0 = 0; s0 < 2048; s0 += 128) {
    __syncthreads();
#pragma unroll
    for (int p = 0; p < 4; ++p) {
      int f = p * 256 + tid;
      int r = f >> 3, c4 = f & 7;
      *(float4*)&ks[r][c4 * 4] =
          *(const float4*)&qb[(size_t)(s0 + r) * 64 + 32 + c4 * 4];
    }
    __syncthreads();
#pragma unroll
    for (int j = 0; j < 8; ++j) {
      int srow = j * 16 + sl;
      float accv = 0.f;
#pragma unroll
      for (int k4 = 0; k4 < 8; ++k4) {
        float4 kv = *(const float4*)&ks[srow][k4 * 4];
        accv += qv[k4 * 4 + 0] * kv.x + qv[k4 * 4 + 1] * kv.y +
                qv[k4 * 4 + 2] * kv.z + qv[k4 * 4 + 3] * kv.w;
      }
      ins4(accv, s0 + srow, v0, i0, v1, i1, v2, i2, v3, i3);
    }
  }
  mv[tl][sl][0] = v0; mv[tl][sl][1] = v1; mv[tl][sl][2] = v2; mv[tl][sl][3] = v3;
  mi[tl][sl][0] = i0; mi[tl][sl][1] = i1; mi[tl][sl][2] = i2; mi[tl][sl][3] = i3;
  __syncthreads();
  if (tid < 16) {
    float w0 = -INFINITY, w1 = -INFINITY, w2 = -INFINITY, w3 = -INFINITY;
    int a0 = 0x7fffffff, a1 = 0x7fffffff, a2 = 0x7fffffff, a3 = 0x7fffffff;
    for (int ss = 0; ss < 16; ++ss)
#pragma unroll
      for (int q = 0; q < 4; ++q)
        ins4(mv[tid][ss][q], mi[tid][ss][q], w0, a0, w1, a1, w2, a2, w3, a3);
    int4 o; o.x = a0; o.y = a1; o.z = a2; o.w = a3;
    *(int4*)&idxout[((size_t)(b * 2048 + t0 + tid)) * 4] = o;
  }
}

__global__ __launch_bounds__(128)
void gather_kernel(const float* __restrict__ x, const int* __restrict__ idx,
                   float* __restrict__ gf, unsigned short* __restrict__ gb) {
  int bt = blockIdx.x;
  int b = bt >> 11;
  const int4 iv = *(const int4*)&idx[(size_t)bt * 4];
  int tid = threadIdx.x;
  const float* xb = x + ((size_t)b * 2048) * 512;
  float4 p0 = *(const float4*)&xb[(size_t)iv.x * 512 + tid * 4];
  float4 p1 = *(const float4*)&xb[(size_t)iv.y * 512 + tid * 4];
  float4 p2 = *(const float4*)&xb[(size_t)iv.z * 512 + tid * 4];
  float4 p3 = *(const float4*)&xb[(size_t)iv.w * 512 + tid * 4];
  float4 m;
  m.x = (p0.x + p1.x + p2.x + p3.x) * 0.25f;
  m.y = (p0.y + p1.y + p2.y + p3.y) * 0.25f;
  m.z = (p0.z + p1.z + p2.z + p3.z) * 0.25f;
  m.w = (p0.w + p1.w + p2.w + p3.w) * 0.25f;
  *(float4*)&gf[(size_t)bt * 512 + tid * 4] = m;
  ushort4 u; u.x = f2b(m.x); u.y = f2b(m.y); u.z = f2b(m.z); u.w = f2b(m.w);
  *(ushort4*)&gb[(size_t)bt * 512 + tid * 4] = u;
}

// ---------------- MFMA GEMM: C = A[MxK] * Bt[NxK]^T (+bias, epilogues) ------
// MODE 0: out bf16 = gelu(acc+bias)   MODE 1: out f32 = acc+bias+resid
// MODE 2: out f32 = acc+bias

template <int MODE>
__global__ __launch_bounds__(256, 2)
void gemm_bf16_k(const unsigned short* __restrict__ A,
                 const unsigned short* __restrict__ Bt,
                 const float* __restrict__ bias,
                 const float* __restrict__ resid,
                 void* __restrict__ outp, int M, int N, int K) {
  __shared__ unsigned short sA[128 * 32];
  __shared__ unsigned short sB[128 * 32];
  const int tid = threadIdx.x;
  const int lane = tid & 63, wave = tid >> 6;
  const int m0 = blockIdx.x * 128, n0 = blockIdx.y * 128;
  const int col16 = lane & 15, quad = lane >> 4;
  const int wm = wave >> 1, wn = wave & 1;
  f32x4v acc[4][4];
#pragma unroll
  for (int i = 0; i < 4; ++i)
#pragma unroll
    for (int j = 0; j < 4; ++j) {
      f32x4v z = {0.f, 0.f, 0.f, 0.f};
      acc[i][j] = z;
    }
  const int nkt = K >> 5;
  for (int kt = 0; kt < nkt; ++kt) {
    const int k0 = kt << 5;
#pragma unroll
    for (int p = 0; p < 2; ++p) {
      int f = p * 256 + tid;
      int row = f >> 2, q4 = f & 3;
      *(uint4*)&sA[row * 32 + q4 * 8] =
          *(const uint4*)(A + (size_t)(m0 + row) * K + k0 + q4 * 8);
      *(uint4*)&sB[row * 32 + q4 * 8] =
          *(const uint4*)(Bt + (size_t)(n0 + row) * K + k0 + q4 * 8);
    }
    __syncthreads();
    bf16x8 af[4], bfr[4];
#pragma unroll
    for (int i = 0; i < 4; ++i)
      af[i] = *(const bf16x8*)&sA[(wm * 64 + i * 16 + col16) * 32 + quad * 8];
#pragma unroll
    for (int j = 0; j < 4; ++j)
      bfr[j] = *(const bf16x8*)&sB[(wn * 64 + j * 16 + col16) * 32 + quad * 8];
#pragma unroll
    for (int i = 0; i < 4; ++i)
#pragma unroll
      for (int j = 0; j < 4; ++j)
        acc[i][j] = __builtin_amdgcn_mfma_f32_16x16x32_bf16(af[i], bfr[j],
                                                            acc[i][j], 0, 0, 0);
    __syncthreads();
  }
  float* outf = (float*)outp;
  unsigned short* outb = (unsigned short*)outp;
#pragma unroll
  for (int i = 0; i < 4; ++i)
#pragma unroll
    for (int j = 0; j < 4; ++j) {
      int col = n0 + wn * 64 + j * 16 + col16;
      float bs = bias[col];
#pragma unroll
      for (int r = 0; r < 4; ++r) {
        int row = m0 + wm * 64 + i * 16 + quad * 4 + r;
        float v = acc[i][j][r] + bs;
        if (MODE == 0) {
          outb[(size_t)row * N + col] = f2b(gelu_f(v));
        } else if (MODE == 1) {
          outf[(size_t)row * N + col] = v + resid[(size_t)row * N + col];
        } else {
          outf[(size_t)row * N + col] = v;
        }
      }
    }
}

// ---------------- LayerNorm (row-wise, fp32 -> bf16) ----------------

__global__ __launch_bounds__(128)
void ln_kernel(const float* __restrict__ ypre, const float* __restrict__ lg,
               const float* __restrict__ lb, unsigned short* __restrict__ yb) {
  int row = blockIdx.x, tid = threadIdx.x;
  float4 v = *(const float4*)&ypre[(size_t)row * 512 + tid * 4];
  float s = v.x + v.y + v.z + v.w;
  float sq = v.x * v.x + v.y * v.y + v.z * v.z + v.w * v.w;
#pragma unroll
  for (int off = 1; off < 64; off <<= 1) {
    s += __shfl_xor(s, off, 64);
    sq += __shfl_xor(sq, off, 64);
  }
  __shared__ float red[4];
  if ((tid & 63) == 0) { red[(tid >> 6) * 2] = s; red[(tid >> 6) * 2 + 1] = sq; }
  __syncthreads();
  float S = red[0] + red[2], SQ = red[1] + red[3];
  float mu = S * (1.f / 512.f);
  float var = SQ * (1.f / 512.f) - mu * mu;
  float rstd = rsqrtf(var + 1e-5f);
  float4 g4 = *(const float4*)&lg[tid * 4];
  float4 b4 = *(const float4*)&lb[tid * 4];
  ushort4 u;
  u.x = f2b((v.x - mu) * rstd * g4.x + b4.x);
  u.y = f2b((v.y - mu) * rstd * g4.y + b4.y);
  u.z = f2b((v.z - mu) * rstd * g4.z + b4.z);
  u.w = f2b((v.w - mu) * rstd * g4.w + b4.w);
  *(ushort4*)&yb[(size_t)row * 512 + tid * 4] = u;
}

// ---------------- System2: persistent serial scan --------------------------
// 8 teams x 32 WGs x 256 thr. TEAMS ARE FORMED BY PHYSICAL XCD (v5):
// each WG reads its chiplet id via s_getreg(HW_REG_XCC_ID) [HW-verified,
// learn_hip m09] and claims (team = xcc, g = fetch_add(cnt[xcc])). With
// 140KB LDS the kernel is exactly 1 WG/CU and grid=256 fills all 256 CUs,
// so each XCD hosts exactly 32 WGs regardless of dispatch order; the spill
// path covers pathological placements anyway. Claim ordering: the cnt RMW's
// response is awaited (s_waitcnt vmcnt(0)) before the done RMW issues, so
// done==256 implies all cnt increments are LLC-performed.
//
// TIER: a team is PURE iff cnt[team] >= 32 (all 32 slots claimed locally).
// Pure teams exchange via their XCD's shared 4MiB L2 (~300cy RTT): plain
// write-through stores + sc0 (L1-bypass) poll loads. Impure teams use the
// proven R2 agent-scope/LLC tagged protocol. Tier is decided ONCE per team
// before the loop -- the R3 lesson: per-thread timeout flips create
// persistent mixed-tier churn (plain stores sit dirty in a remote L2,
// invisible at the LLC until eviction -> every step stalls ~10-25us).
// Parachute for "mechanism broken": a poll stuck 2048 iterations raises a
// TEAM-WIDE abort flag (LLC); all members flip to the LLC tier together and
// republish their retained words (both parities) -- one bounded transition.
//
// Payload protocol (unchanged from R2): tagged words (tag<<32)|float_bits,
// tag = s+1, parity double-buffer; 8B single-copy atomicity means the tag
// travels with the data -- no flags, no drains, no fences. Stale content
// (tag s-1) and 0xAA poison (tag 0xAAAAAAAA) never match the expected tag.

__global__ __launch_bounds__(256)
void system2_kernel(const float* __restrict__ Wt1, const float* __restrict__ Wt2T,
                    const float* __restrict__ bt2, const float* __restrict__ xpart,
                    ull* __restrict__ guT, ull* __restrict__ memT,
                    int* __restrict__ claim, float* __restrict__ memfinal) {
  __shared__ float WbT[32 * 516];    // stage1 W [j][k], stride 516 (66048 B)
  __shared__ float W2S[16 * 1028];   // stage2 W [dd][u], stride 1028 (65792 B)
  __shared__ float memS[512];
  __shared__ float guA[1024];
  __shared__ float parts1[256];      // [c][j] = [8][32]
  __shared__ float red2[256];        // [c2][dd] = [16][16]
  __shared__ int sTG[3];

  const int t = threadIdx.x;

  // ---- one-time claim: (team, g) from physical XCD ----
  if (t == 0) {
    int xcc = 0;
    asm volatile("s_getreg_b32 %0, hwreg(HW_REG_XCC_ID)" : "=s"(xcc));
    xcc &= 7;
    int* cnt = claim;            // [0..7]
    int* spillIdx = claim + 8;
    int* done = claim + 9;
    int pos = __hip_atomic_fetch_add(&cnt[xcc], 1, __ATOMIC_RELAXED,
                                     __HIP_MEMORY_SCOPE_AGENT);
    int spill = -1, team = xcc, g = pos;
    if (pos >= 32)
      spill = __hip_atomic_fetch_add(spillIdx, 1, __ATOMIC_RELAXED,
                                     __HIP_MEMORY_SCOPE_AGENT);
    // ensure claim RMWs are LLC-performed before done increments
    asm volatile("s_waitcnt vmcnt(0)" ::: "memory");
    __hip_atomic_fetch_add(done, 1, __ATOMIC_RELAXED, __HIP_MEMORY_SCOPE_AGENT);
    while (__hip_atomic_load(done, __ATOMIC_RELAXED,
                             __HIP_MEMORY_SCOPE_AGENT) < 256)
      __builtin_amdgcn_s_sleep(8);
    int cs[8];
#pragma unroll
    for (int x = 0; x < 8; ++x)
      cs[x] = __hip_atomic_load(&cnt[x], __ATOMIC_RELAXED,
                                __HIP_MEMORY_SCOPE_AGENT);
    if (spill >= 0) {
      int k = spill;
      for (int x = 0; x < 8; ++x) {
        int have = cs[x] < 32 ? cs[x] : 32;
        int def = 32 - have;
        if (k < def) { team = x; g = have + k; break; }
        k -= def;
      }
    }
    sTG[0] = team;
    sTG[1] = g;
    sTG[2] = (cs[team] >= 32) ? 0 : 1;   // 0 = fast (pure team), 1 = LLC
  }
  __syncthreads();
  const int team = sTG[0];
  const int g = sTG[1];
  int slowR = sTG[2];
  int* abortF = claim + 10 + team;
  const int ucol0 = g << 5;
  const int mcol0 = g << 4;

  // ---- load weights into LDS (one-time) ----
  for (int idx = t; idx < 32 * 512; idx += 256) {
    int j = idx & 31, k = idx >> 5;
    WbT[j * 516 + k] = Wt1[(size_t)(512 + k) * 1024 + ucol0 + j];
  }
  for (int idx = t; idx < 16 * 1024; idx += 256) {
    int dd = idx >> 10, u = idx & 1023;
    W2S[dd * 1028 + u] = Wt2T[(size_t)(mcol0 + dd) * 1024 + u];
  }
  memS[t] = 0.f;
  memS[t + 256] = 0.f;
  const float bt2r = (t < 16) ? bt2[mcol0 + t] : 0.f;
  __syncthreads();

  const int j = t & 31, c = t >> 5;        // stage1 roles: col j, k-chunk c(8)
  const int dd = t & 15, c2 = t >> 4;      // stage2 roles: col dd, u-chunk c2(16)
  const float* xp = xpart + (size_t)team * 2048 * 1024 + ucol0;
  float xv = (t < 32) ? xp[t] : 0.f;

  // retained last-written words for abort republish
  ull guW0 = 0, guW1 = 0, memW0 = 0, memW1 = 0;
  const int NET = 2048;

  auto republish = [&]() {
    if (t < 32) {
      __hip_atomic_store(guT + (size_t)(0 * 8 + team) * 1024 + ucol0 + t, guW0,
                         __ATOMIC_RELAXED, __HIP_MEMORY_SCOPE_AGENT);
      __hip_atomic_store(guT + (size_t)(1 * 8 + team) * 1024 + ucol0 + t, guW1,
                         __ATOMIC_RELAXED, __HIP_MEMORY_SCOPE_AGENT);
    }
    if (t < 16) {
      __hip_atomic_store(memT + (size_t)(0 * 8 + team) * 512 + mcol0 + t, memW0,
                         __ATOMIC_RELAXED, __HIP_MEMORY_SCOPE_AGENT);
      __hip_atomic_store(memT + (size_t)(1 * 8 + team) * 512 + mcol0 + t, memW1,
                         __ATOMIC_RELAXED, __HIP_MEMORY_SCOPE_AGENT);
    }
  };

  for (int s = 0; s < 2048; ++s) {
    const int par = s & 1;
    ull* gub = guT + (size_t)(par * 8 + team) * 1024;
    ull* memb = memT + (size_t)(par * 8 + team) * 512;
    const unsigned utag = (unsigned)(s + 1);
    const ull tagw = ((ull)utag) << 32;

    // ---- stage1: u[ucol0+j] partial over k-chunk c (64 k), float4 LDS ----
    {
      const float* wrow = &WbT[j * 516 + c * 64];
      const float* mrow = &memS[c * 64];
      float p1 = 0.f;
#pragma unroll
      for (int i = 0; i < 64; i += 4) {
        float4 wv = *(const float4*)&wrow[i];
        float4 mv = *(const float4*)&mrow[i];
        p1 += wv.x * mv.x + wv.y * mv.y + wv.z * mv.z + wv.w * mv.w;
      }
      parts1[c * 32 + j] = p1;
    }
    __syncthreads();
    // ---- own 32 gu values: reduce, gelu, tagged broadcast store ----
    if (t < 32) {
      float u = xv;   // xpart includes xt@Wt1[:512] + bt1
#pragma unroll
      for (int cc = 0; cc < 8; ++cc) u += parts1[cc * 32 + t];
      float gv = gelu_f(u);
      union { float f; unsigned u; } uv; uv.f = gv;
      ull w = tagw | uv.u;
      if (par) guW1 = w; else guW0 = w;
      if (slowR)
        __hip_atomic_store(&gub[ucol0 + t], w, __ATOMIC_RELAXED,
                           __HIP_MEMORY_SCOPE_AGENT);
      else
        st_l2_u64(&gub[ucol0 + t], w);
    }
    asm volatile("" ::: "memory");  // compiler-only: stores before polls

    // ---- poll full gu (4 tagged words per thread) -> guA ----
    {
      ull* p = &gub[t * 4];
      ull v0, v1, v2, v3;
      int it = 0;
      for (;;) {
        if (slowR) {
          v0 = __hip_atomic_load(&p[0], __ATOMIC_RELAXED, __HIP_MEMORY_SCOPE_AGENT);
          v1 = __hip_atomic_load(&p[1], __ATOMIC_RELAXED, __HIP_MEMORY_SCOPE_AGENT);
          v2 = __hip_atomic_load(&p[2], __ATOMIC_RELAXED, __HIP_MEMORY_SCOPE_AGENT);
          v3 = __hip_atomic_load(&p[3], __ATOMIC_RELAXED, __HIP_MEMORY_SCOPE_AGENT);
        } else {
          ld4_l2_u64(p, v0, v1, v2, v3);
        }
        bool ok = ((unsigned)(v0 >> 32) == utag) & ((unsigned)(v1 >> 32) == utag) &
                  ((unsigned)(v2 >> 32) == utag) & ((unsigned)(v3 >> 32) == utag);
        if (ok) break;
        ++it;
        if (!slowR) {
          if (it == NET)
            __hip_atomic_store(abortF, 1, __ATOMIC_RELAXED,
                               __HIP_MEMORY_SCOPE_AGENT);
          if ((it & 255) == 0 &&
              __hip_atomic_load(abortF, __ATOMIC_RELAXED,
                                __HIP_MEMORY_SCOPE_AGENT)) {
            slowR = 1;
            republish();
          }
        }
        __builtin_amdgcn_s_sleep(1);
      }
      union { unsigned u; float f; } a0, a1, a2, a3;
      a0.u = (unsigned)v0; a1.u = (unsigned)v1;
      a2.u = (unsigned)v2; a3.u = (unsigned)v3;
      guA[t * 4 + 0] = a0.f;
      guA[t * 4 + 1] = a1.f;
      guA[t * 4 + 2] = a2.f;
      guA[t * 4 + 3] = a3.f;
    }
    // xpart prefetch HERE: keeps its ~900cy HBM latency out of poll-A's
    // vmcnt(0); hidden under stage2 + round B.
    float xnext = (t < 32 && s < 2047) ? xp[(size_t)(s + 1) * 1024 + t] : 0.f;
    __syncthreads();

    // ---- stage2: full prop for own col (mcol0+dd), u-chunk c2 (64 u) ----
    {
      const float* wrow = &W2S[dd * 1028 + c2 * 64];
      const float* grow = &guA[c2 * 64];
      float p2 = 0.f;
#pragma unroll
      for (int i = 0; i < 64; i += 4) {
        float4 wv = *(const float4*)&wrow[i];
        float4 gv = *(const float4*)&grow[i];
        p2 += wv.x * gv.x + wv.y * gv.y + wv.z * gv.z + wv.w * gv.w;
      }
      red2[c2 * 16 + dd] = p2;
    }
    __syncthreads();
    // ---- own 16 mem-cols: reduce 16 chunks, gate, tagged mem store ----
    if (t < 16) {
      float prop = bt2r;
#pragma unroll
      for (int cc = 0; cc < 16; ++cc) prop += red2[cc * 16 + t];
      float gate = 1.f / (1.f + __expf(-prop));
      float mnew = memS[mcol0 + t] * (1.f - gate) + prop * gate;
      union { float f; unsigned u; } mv; mv.f = mnew;
      ull w = tagw | mv.u;
      if (par) memW1 = w; else memW0 = w;
      if (slowR)
        __hip_atomic_store(&memb[mcol0 + t], w, __ATOMIC_RELAXED,
                           __HIP_MEMORY_SCOPE_AGENT);
      else
        st_l2_u64(&memb[mcol0 + t], w);
    }
    asm volatile("" ::: "memory");

    // ---- poll full mem (2 tagged words per thread) -> memS ----
    {
      ull* q = &memb[t * 2];
      ull v1, v2;
      int it = 0;
      for (;;) {
        if (slowR) {
          v1 = __hip_atomic_load(&q[0], __ATOMIC_RELAXED, __HIP_MEMORY_SCOPE_AGENT);
          v2 = __hip_atomic_load(&q[1], __ATOMIC_RELAXED, __HIP_MEMORY_SCOPE_AGENT);
        } else {
          ld2_l2_u64(q, v1, v2);
        }
        if (((unsigned)(v1 >> 32) == utag) & ((unsigned)(v2 >> 32) == utag)) break;
        ++it;
        if (!slowR) {
          if (it == NET)
            __hip_atomic_store(abortF, 1, __ATOMIC_RELAXED,
                               __HIP_MEMORY_SCOPE_AGENT);
          if ((it & 255) == 0 &&
              __hip_atomic_load(abortF, __ATOMIC_RELAXED,
                                __HIP_MEMORY_SCOPE_AGENT)) {
            slowR = 1;
            republish();
          }
        }
        __builtin_amdgcn_s_sleep(1);
      }
      union { unsigned u; float f; } m1, m2;
      m1.u = (unsigned)v1; m2.u = (unsigned)v2;
      memS[t * 2] = m1.f;
      memS[t * 2 + 1] = m2.f;
    }
    xv = xnext;
    __syncthreads();
  }

  if (g == 0 && t < 128)
    *(float4*)&memfinal[(size_t)team * 512 + t * 4] = *(float4*)&memS[t * 4];
}

// ---------------- output GEMV ----------------

__global__ __launch_bounds__(256)
void out_gemv_kernel(const float* __restrict__ memf, const float* __restrict__ Wo,
                     const float* __restrict__ bo, float* __restrict__ out) {
  int gid = blockIdx.x * 256 + threadIdx.x;   // 4096 total
  int b = gid >> 9, d = gid & 511;
  const float* mb = memf + (size_t)b * 512;
  float acc = bo[d];
#pragma unroll 8
  for (int k = 0; k < 512; ++k) acc += mb[k] * Wo[(size_t)k * 512 + d];
  out[gid] = acc;
}

// ---------------- launch ----------------

extern "C" void kernel_launch(void* const* d_in, const int* in_sizes, int n_in,
                              void* d_out, int out_size, void* d_ws, size_t ws_size,
                              hipStream_t stream) {
  const float* x   = (const float*)d_in[0];
  const float* Wq  = (const float*)d_in[1];
  const float* bq  = (const float*)d_in[2];
  const float* Wk  = (const float*)d_in[3];
  const float* bk  = (const float*)d_in[4];
  const float* W1  = (const float*)d_in[5];
  const float* b1  = (const float*)d_in[6];
  const float* W2  = (const float*)d_in[7];
  const float* b2  = (const float*)d_in[8];
  const float* lng = (const float*)d_in[9];
  const float* lnb = (const float*)d_in[10];
  const float* Wt1 = (const float*)d_in[11];
  const float* bt1 = (const float*)d_in[12];
  const float* Wt2 = (const float*)d_in[13];
  const float* bt2 = (const float*)d_in[14];
  const float* Wo  = (const float*)d_in[15];
  const float* bo  = (const float*)d_in[16];
  float* out = (float*)d_out;

  char* ws = (char*)d_ws;
  size_t off = 0;
  auto alloc = [&](size_t bytes) -> void* {
    void* p = ws + off;
    off += (bytes + 255) & ~(size_t)255;
    return p;
  };
  float* qk             = (float*)alloc(8ull * 2048 * 64 * 4);
  int* idxb             = (int*)alloc(8ull * 2048 * 4 * 4);
  float* gathf          = (float*)alloc(16384ull * 512 * 4);
  unsigned short* gathb = (unsigned short*)alloc(16384ull * 512 * 2);
  unsigned short* h1b   = (unsigned short*)alloc(16384ull * 1024 * 2);
  float* ypre           = (float*)alloc(16384ull * 512 * 4);
  unsigned short* yb    = (unsigned short*)alloc(16384ull * 512 * 2);
  float* xpart          = (float*)alloc(16384ull * 1024 * 4);
  unsigned short* w1t   = (unsigned short*)alloc(1024ull * 512 * 2);
  unsigned short* w2t   = (unsigned short*)alloc(512ull * 1024 * 2);
  unsigned short* wt1t  = (unsigned short*)alloc(1024ull * 512 * 2);
  float* wt2t           = (float*)alloc(512ull * 1024 * 4);      // Wt2^T fp32
  float* wqkb           = (float*)alloc(512ull * 64 * 4);
  ull* guT              = (ull*)alloc(2ull * 8 * 1024 * 8);      // 128 KB
  ull* memT             = (ull*)alloc(2ull * 8 * 512 * 8);       // 64 KB
  int* claimb           = (int*)alloc(64ull * 4);
  float* memf           = (float*)alloc(8ull * 512 * 4);
  if (off > ws_size) return;  // workspace too small -> visible bench failure

  zero_kernel<<<1, 64, 0, stream>>>(claimb);
  wqk_kernel<<<128, 256, 0, stream>>>(Wq, Wk, wqkb);
  transpose_bf16_kernel<<<dim3(16, 32), 256, 0, stream>>>(W1, w1t, 512, 1024);
  transpose_bf16_kernel<<<dim3(32, 16), 256, 0, stream>>>(W2, w2t, 1024, 512);
  transpose_bf16_kernel<<<dim3(16, 32), 256, 0, stream>>>(Wt1, wt1t, 512, 1024);
  transpose_f32_kernel<<<dim3(32, 16), 256, 0, stream>>>(Wt2, wt2t, 1024, 512);

  qk_kernel<<<1024, 256, 0, stream>>>(x, wqkb, bq, bk, qk);
  topk_kernel<<<1024, 256, 0, stream>>>(qk, idxb);
  gather_kernel<<<16384, 128, 0, stream>>>(x, idxb, gathf, gathb);

  gemm_bf16_k<0><<<dim3(128, 8), 256, 0, stream>>>(gathb, w1t, b1, nullptr, h1b,
                                                   16384, 1024, 512);
  gemm_bf16_k<1><<<dim3(128, 4), 256, 0, stream>>>(h1b, w2t, b2, gathf, ypre,
                                                   16384, 512, 1024);
  ln_kernel<<<16384, 128, 0, stream>>>(ypre, lng, lnb, yb);
  gemm_bf16_k<2><<<dim3(128, 8), 256, 0, stream>>>(yb, wt1t, bt1, nullptr, xpart,
                                                   16384, 1024, 512);

  system2_kernel<<<256, 256, 0, stream>>>(Wt1, wt2t, bt2, xpart, guT, memT,
                                          claimb, memf);
  out_gemv_kernel<<<16, 256, 0, stream>>>(memf, Wo, bo, out);
}

// Round 5
// 10096.162 us; speedup vs baseline: 2.4702x; 1.1660x over previous
//
#include <hip/hip_runtime.h>
#include <math.h>
#include <stdint.h>

// ---------------------------------------------------------------------------
// InvertedCognitionModel: B=8, T=2048, D=512, KQ=32, K=4
//   router (fp32 sim + top4, fused) -> gather-mean -> FFN+LN (bf16 MFMA)
//   -> serial gated memory scan: 4 teams x 32 WGs, each team runs TWO
//      sequences interleaved (latency hiding); proven R2 tagged-LLC sync
//   -> output GEMV
// ---------------------------------------------------------------------------

using bf16x8 = __attribute__((ext_vector_type(8))) short;
using f32x4v = __attribute__((ext_vector_type(4))) float;
typedef unsigned long long ull;

__device__ inline unsigned short f2b(float f) {
  union { float f; unsigned int u; } v; v.f = f;
  unsigned int r = v.u + 0x7fffu + ((v.u >> 16) & 1u);   // RNE
  return (unsigned short)(r >> 16);
}

__device__ inline float gelu_f(float x) {
  return 0.5f * x * (1.0f + erff(x * 0.70710678118654752f));
}

// sorted-descending top-4 insert, tie-break lower index first
__device__ inline void ins4(float v, int i,
                            float& v0, int& i0, float& v1, int& i1,
                            float& v2, int& i2, float& v3, int& i3) {
  bool b0 = (v > v0) || (v == v0 && i < i0);
  bool b1 = (v > v1) || (v == v1 && i < i1);
  bool b2 = (v > v2) || (v == v2 && i < i2);
  bool b3 = (v > v3) || (v == v3 && i < i3);
  float nv3 = b2 ? v2 : (b3 ? v : v3); int ni3 = b2 ? i2 : (b3 ? i : i3);
  float nv2 = b1 ? v1 : (b2 ? v : v2); int ni2 = b1 ? i1 : (b2 ? i : i2);
  float nv1 = b0 ? v0 : (b1 ? v : v1); int ni1 = b0 ? i0 : (b1 ? i : i1);
  float nv0 = b0 ? v  : v0;            int ni0 = b0 ? i  : i0;
  v0=nv0; i0=ni0; v1=nv1; i1=ni1; v2=nv2; i2=ni2; v3=nv3; i3=ni3;
}

// ---------------- prep kernels ----------------

__global__ __launch_bounds__(256)
void wqk_kernel(const float* __restrict__ Wq, const float* __restrict__ Wk,
                float* __restrict__ wqk) {
  int id = blockIdx.x * 256 + threadIdx.x;        // < 512*64
  int d = id >> 6, c = id & 63;
  wqk[id] = (c < 32) ? Wq[d * 32 + c] : Wk[d * 32 + (c - 32)];
}

// dst[n][k] = bf16(src[k][n]); src is [>=K x N] row-major, dst [N x K]
__global__ __launch_bounds__(256)
void transpose_bf16_kernel(const float* __restrict__ src,
                           unsigned short* __restrict__ dst, int K, int N) {
  __shared__ float tile[32][33];
  int bk = blockIdx.x << 5, bn = blockIdx.y << 5;
  int c = threadIdx.x & 31, r8 = threadIdx.x >> 5;
  for (int r = r8; r < 32; r += 8) tile[r][c] = src[(size_t)(bk + r) * N + bn + c];
  __syncthreads();
  for (int r = r8; r < 32; r += 8) dst[(size_t)(bn + r) * K + bk + c] = f2b(tile[c][r]);
}

// dst[n][k] = src[k][n] (fp32), for coalesced LDS staging of Wt2 columns
__global__ __launch_bounds__(256)
void transpose_f32_kernel(const float* __restrict__ src,
                          float* __restrict__ dst, int K, int N) {
  __shared__ float tile[32][33];
  int bk = blockIdx.x << 5, bn = blockIdx.y << 5;
  int c = threadIdx.x & 31, r8 = threadIdx.x >> 5;
  for (int r = r8; r < 32; r += 8) tile[r][c] = src[(size_t)(bk + r) * N + bn + c];
  __syncthreads();
  for (int r = r8; r < 32; r += 8) dst[(size_t)(bn + r) * K + bk + c] = tile[c][r];
}

// ---------------- router ----------------

// q|k projection: qkout[b,t,0:32]=q, [32:64]=k (fp32, biases included)
__global__ __launch_bounds__(256)
void qk_kernel(const float* __restrict__ x, const float* __restrict__ wqk,
               const float* __restrict__ bq, const float* __restrict__ bk,
               float* __restrict__ qkout) {
  __shared__ float xs[16][512];
  int tid = threadIdx.x;
  int b = blockIdx.x >> 7;
  int t0 = (blockIdx.x & 127) << 4;
  const float* xb = x + ((size_t)(b * 2048 + t0)) * 512;
#pragma unroll
  for (int i = 0; i < 8; ++i) {
    int f = i * 256 + tid;
    int r = f >> 7, c4 = f & 127;
    *(float4*)&xs[r][c4 * 4] = *(const float4*)&xb[(size_t)r * 512 + c4 * 4];
  }
  __syncthreads();
  int c = tid & 63, r4 = tid >> 6;
  float a0 = 0.f, a1 = 0.f, a2 = 0.f, a3 = 0.f;
#pragma unroll 4
  for (int d = 0; d < 512; ++d) {
    float w = wqk[d * 64 + c];
    a0 += xs[r4][d] * w;
    a1 += xs[r4 + 4][d] * w;
    a2 += xs[r4 + 8][d] * w;
    a3 += xs[r4 + 12][d] * w;
  }
  float bias = (c < 32) ? bq[c] : bk[c - 32];
  size_t base = ((size_t)(b * 2048 + t0)) * 64 + c;
  qkout[base + (size_t)r4 * 64] = a0 + bias;
  qkout[base + (size_t)(r4 + 4) * 64] = a1 + bias;
  qkout[base + (size_t)(r4 + 8) * 64] = a2 + bias;
  qkout[base + (size_t)(r4 + 12) * 64] = a3 + bias;
}

// fused sim + top-4: block = 16 query rows; never materializes sim
__global__ __launch_bounds__(256)
void topk_kernel(const float* __restrict__ qkb, int* __restrict__ idxout) {
  __shared__ float qs[16][36];
  __shared__ float ks[128][36];
  __shared__ float mv[16][16][4];
  __shared__ int   mi[16][16][4];
  int tid = threadIdx.x;
  int b = blockIdx.x >> 7;
  int t0 = (blockIdx.x & 127) << 4;
  const float* qb = qkb + ((size_t)b * 2048) * 64;
  if (tid < 128) {
    int r = tid >> 3, c4 = tid & 7;
    *(float4*)&qs[r][c4 * 4] = *(const float4*)&qb[(size_t)(t0 + r) * 64 + c4 * 4];
  }
  __syncthreads();
  int tl = tid >> 4, sl = tid & 15;
  float qv[32];
#pragma unroll
  for (int kk = 0; kk < 32; ++kk) qv[kk] = qs[tl][kk];
  float v0 = -INFINITY, v1 = -INFINITY, v2 = -INFINITY, v3 = -INFINITY;
  int i0 = 0x7fffffff, i1 = 0x7fffffff, i2 = 0x7fffffff, i3 = 0x7fffffff;
  for (int s0 = 0; s0 < 2048; s0 += 128) {
    __syncthreads();
#pragma unroll
    for (int p = 0; p < 4; ++p) {
      int f = p * 256 + tid;
      int r = f >> 3, c4 = f & 7;
      *(float4*)&ks[r][c4 * 4] =
          *(const float4*)&qb[(size_t)(s0 + r) * 64 + 32 + c4 * 4];
    }
    __syncthreads();
#pragma unroll
    for (int j = 0; j < 8; ++j) {
      int srow = j * 16 + sl;
      float accv = 0.f;
#pragma unroll
      for (int k4 = 0; k4 < 8; ++k4) {
        float4 kv = *(const float4*)&ks[srow][k4 * 4];
        accv += qv[k4 * 4 + 0] * kv.x + qv[k4 * 4 + 1] * kv.y +
                qv[k4 * 4 + 2] * kv.z + qv[k4 * 4 + 3] * kv.w;
      }
      ins4(accv, s0 + srow, v0, i0, v1, i1, v2, i2, v3, i3);
    }
  }
  mv[tl][sl][0] = v0; mv[tl][sl][1] = v1; mv[tl][sl][2] = v2; mv[tl][sl][3] = v3;
  mi[tl][sl][0] = i0; mi[tl][sl][1] = i1; mi[tl][sl][2] = i2; mi[tl][sl][3] = i3;
  __syncthreads();
  if (tid < 16) {
    float w0 = -INFINITY, w1 = -INFINITY, w2 = -INFINITY, w3 = -INFINITY;
    int a0 = 0x7fffffff, a1 = 0x7fffffff, a2 = 0x7fffffff, a3 = 0x7fffffff;
    for (int ss = 0; ss < 16; ++ss)
#pragma unroll
      for (int q = 0; q < 4; ++q)
        ins4(mv[tid][ss][q], mi[tid][ss][q], w0, a0, w1, a1, w2, a2, w3, a3);
    int4 o; o.x = a0; o.y = a1; o.z = a2; o.w = a3;
    *(int4*)&idxout[((size_t)(b * 2048 + t0 + tid)) * 4] = o;
  }
}

__global__ __launch_bounds__(128)
void gather_kernel(const float* __restrict__ x, const int* __restrict__ idx,
                   float* __restrict__ gf, unsigned short* __restrict__ gb) {
  int bt = blockIdx.x;
  int b = bt >> 11;
  const int4 iv = *(const int4*)&idx[(size_t)bt * 4];
  int tid = threadIdx.x;
  const float* xb = x + ((size_t)b * 2048) * 512;
  float4 p0 = *(const float4*)&xb[(size_t)iv.x * 512 + tid * 4];
  float4 p1 = *(const float4*)&xb[(size_t)iv.y * 512 + tid * 4];
  float4 p2 = *(const float4*)&xb[(size_t)iv.z * 512 + tid * 4];
  float4 p3 = *(const float4*)&xb[(size_t)iv.w * 512 + tid * 4];
  float4 m;
  m.x = (p0.x + p1.x + p2.x + p3.x) * 0.25f;
  m.y = (p0.y + p1.y + p2.y + p3.y) * 0.25f;
  m.z = (p0.z + p1.z + p2.z + p3.z) * 0.25f;
  m.w = (p0.w + p1.w + p2.w + p3.w) * 0.25f;
  *(float4*)&gf[(size_t)bt * 512 + tid * 4] = m;
  ushort4 u; u.x = f2b(m.x); u.y = f2b(m.y); u.z = f2b(m.z); u.w = f2b(m.w);
  *(ushort4*)&gb[(size_t)bt * 512 + tid * 4] = u;
}

// ---------------- MFMA GEMM: C = A[MxK] * Bt[NxK]^T (+bias, epilogues) ------
// MODE 0: out bf16 = gelu(acc+bias)   MODE 1: out f32 = acc+bias+resid
// MODE 2: out f32 = acc+bias

template <int MODE>
__global__ __launch_bounds__(256, 2)
void gemm_bf16_k(const unsigned short* __restrict__ A,
                 const unsigned short* __restrict__ Bt,
                 const float* __restrict__ bias,
                 const float* __restrict__ resid,
                 void* __restrict__ outp, int M, int N, int K) {
  __shared__ unsigned short sA[128 * 32];
  __shared__ unsigned short sB[128 * 32];
  const int tid = threadIdx.x;
  const int lane = tid & 63, wave = tid >> 6;
  const int m0 = blockIdx.x * 128, n0 = blockIdx.y * 128;
  const int col16 = lane & 15, quad = lane >> 4;
  const int wm = wave >> 1, wn = wave & 1;
  f32x4v acc[4][4];
#pragma unroll
  for (int i = 0; i < 4; ++i)
#pragma unroll
    for (int j = 0; j < 4; ++j) {
      f32x4v z = {0.f, 0.f, 0.f, 0.f};
      acc[i][j] = z;
    }
  const int nkt = K >> 5;
  for (int kt = 0; kt < nkt; ++kt) {
    const int k0 = kt << 5;
#pragma unroll
    for (int p = 0; p < 2; ++p) {
      int f = p * 256 + tid;
      int row = f >> 2, q4 = f & 3;
      *(uint4*)&sA[row * 32 + q4 * 8] =
          *(const uint4*)(A + (size_t)(m0 + row) * K + k0 + q4 * 8);
      *(uint4*)&sB[row * 32 + q4 * 8] =
          *(const uint4*)(Bt + (size_t)(n0 + row) * K + k0 + q4 * 8);
    }
    __syncthreads();
    bf16x8 af[4], bfr[4];
#pragma unroll
    for (int i = 0; i < 4; ++i)
      af[i] = *(const bf16x8*)&sA[(wm * 64 + i * 16 + col16) * 32 + quad * 8];
#pragma unroll
    for (int j = 0; j < 4; ++j)
      bfr[j] = *(const bf16x8*)&sB[(wn * 64 + j * 16 + col16) * 32 + quad * 8];
#pragma unroll
    for (int i = 0; i < 4; ++i)
#pragma unroll
      for (int j = 0; j < 4; ++j)
        acc[i][j] = __builtin_amdgcn_mfma_f32_16x16x32_bf16(af[i], bfr[j],
                                                            acc[i][j], 0, 0, 0);
    __syncthreads();
  }
  float* outf = (float*)outp;
  unsigned short* outb = (unsigned short*)outp;
#pragma unroll
  for (int i = 0; i < 4; ++i)
#pragma unroll
    for (int j = 0; j < 4; ++j) {
      int col = n0 + wn * 64 + j * 16 + col16;
      float bs = bias[col];
#pragma unroll
      for (int r = 0; r < 4; ++r) {
        int row = m0 + wm * 64 + i * 16 + quad * 4 + r;
        float v = acc[i][j][r] + bs;
        if (MODE == 0) {
          outb[(size_t)row * N + col] = f2b(gelu_f(v));
        } else if (MODE == 1) {
          outf[(size_t)row * N + col] = v + resid[(size_t)row * N + col];
        } else {
          outf[(size_t)row * N + col] = v;
        }
      }
    }
}

// ---------------- LayerNorm (row-wise, fp32 -> bf16) ----------------

__global__ __launch_bounds__(128)
void ln_kernel(const float* __restrict__ ypre, const float* __restrict__ lg,
               const float* __restrict__ lb, unsigned short* __restrict__ yb) {
  int row = blockIdx.x, tid = threadIdx.x;
  float4 v = *(const float4*)&ypre[(size_t)row * 512 + tid * 4];
  float s = v.x + v.y + v.z + v.w;
  float sq = v.x * v.x + v.y * v.y + v.z * v.z + v.w * v.w;
#pragma unroll
  for (int off = 1; off < 64; off <<= 1) {
    s += __shfl_xor(s, off, 64);
    sq += __shfl_xor(sq, off, 64);
  }
  __shared__ float red[4];
  if ((tid & 63) == 0) { red[(tid >> 6) * 2] = s; red[(tid >> 6) * 2 + 1] = sq; }
  __syncthreads();
  float S = red[0] + red[2], SQ = red[1] + red[3];
  float mu = S * (1.f / 512.f);
  float var = SQ * (1.f / 512.f) - mu * mu;
  float rstd = rsqrtf(var + 1e-5f);
  float4 g4 = *(const float4*)&lg[tid * 4];
  float4 b4 = *(const float4*)&lb[tid * 4];
  ushort4 u;
  u.x = f2b((v.x - mu) * rstd * g4.x + b4.x);
  u.y = f2b((v.y - mu) * rstd * g4.y + b4.y);
  u.z = f2b((v.z - mu) * rstd * g4.z + b4.z);
  u.w = f2b((v.w - mu) * rstd * g4.w + b4.w);
  *(ushort4*)&yb[(size_t)row * 512 + tid * 4] = u;
}

// ---------------- System2: persistent serial scan, 2-way interleaved -------
// 4 teams x 32 WGs x 256 thr; blockIdx = g*4 + team. Each team owns TWO
// sequences P = team*2, Q = team*2+1 and interleaves their phases so every
// LLC flight is covered by ~700-1400cy of the other sequence's compute
// (latency hiding by software multithreading; R0-R4 showed the exchange
// latency is irreducible at ~2 LLC RTT/step while ALUs idle at 10%).
//
// Per superstep s (both sequences advance one step):
//   stage1(P) | redA+storeA(P) | pollB(Q,s)->memQ | stage1(Q) |
//   redA+storeA(Q) | pollA(P)->guP | stage2(P) | redB+storeB(P) |
//   pollA(Q)->guQ | stage2(Q) | redB+storeB(Q) | pollB(P,s+1)->memP
// Final pollB(Q,2048) after the loop.
//
// SYNC (verbatim R2, proven): tagged words (tag<<32)|float_bits, tag=s+1,
// relaxed agent-scope 8B atomics (single-copy atomic -> tag travels with
// payload; no flags, no drains, no fences), parity double-buffer per
// sequence. Stale slots hold tag s-1 or 0xAAAAAAAA poison -> never match.
// Overwrite safety (re-derived for the interleave): any store into a slot
// 2 supersteps later is gated through a poll phase that transitively
// requires every WG to have completed the phase that last read that slot.

__global__ __launch_bounds__(256)
void system2_kernel(const float* __restrict__ Wt1, const float* __restrict__ Wt2T,
                    const float* __restrict__ bt2, const float* __restrict__ xpart,
                    ull* __restrict__ guT, ull* __restrict__ memT,
                    float* __restrict__ memfinal) {
  __shared__ float WbT[32 * 516];    // stage1 W [j][k], stride 516 (66048 B)
  __shared__ float W2S[16 * 1028];   // stage2 W [dd][u], stride 1028 (65792 B)
  __shared__ float memP[512], memQ[512];
  __shared__ float guP[1024], guQ[1024];
  __shared__ float parts1P[256], parts1Q[256];
  __shared__ float red2P[256], red2Q[256];

  const int t = threadIdx.x;
  const int team = blockIdx.x & 3;        // 0..3
  const int g = blockIdx.x >> 2;          // 0..31
  const int seqP = team * 2, seqQ = team * 2 + 1;
  const int ucol0 = g << 5;
  const int mcol0 = g << 4;

  // ---- load weights into LDS (one-time) ----
  for (int idx = t; idx < 32 * 512; idx += 256) {
    int j = idx & 31, k = idx >> 5;
    WbT[j * 516 + k] = Wt1[(size_t)(512 + k) * 1024 + ucol0 + j];
  }
  for (int idx = t; idx < 16 * 1024; idx += 256) {
    int dd = idx >> 10, u = idx & 1023;
    W2S[dd * 1028 + u] = Wt2T[(size_t)(mcol0 + dd) * 1024 + u];
  }
  memP[t] = 0.f; memP[t + 256] = 0.f;
  memQ[t] = 0.f; memQ[t + 256] = 0.f;
  const float bt2r = (t < 16) ? bt2[mcol0 + t] : 0.f;
  __syncthreads();

  const int j = t & 31, c = t >> 5;        // stage1 roles: col j, k-chunk c(8)
  const int dd = t & 15, c2 = t >> 4;      // stage2 roles: col dd, u-chunk c2(16)
  const float* xpP = xpart + (size_t)seqP * 2048 * 1024 + ucol0;
  const float* xpQ = xpart + (size_t)seqQ * 2048 * 1024 + ucol0;
  float xvP = (t < 32) ? xpP[t] : 0.f;
  float xvQ = (t < 32) ? xpQ[t] : 0.f;

  for (int s = 0; s < 2048; ++s) {
    const int par = s & 1;
    ull* gubP = guT + (size_t)(par * 8 + seqP) * 1024;
    ull* gubQ = guT + (size_t)(par * 8 + seqQ) * 1024;
    ull* membP = memT + (size_t)(par * 8 + seqP) * 512;
    ull* membQ = memT + (size_t)(par * 8 + seqQ) * 512;
    ull* membQp = memT + (size_t)(((s + 1) & 1) * 8 + seqQ) * 512;  // tag s slot
    const unsigned utag = (unsigned)(s + 1);
    const ull tagw = ((ull)utag) << 32;

    // [1] stage1(P): parts over k-chunk c (64 k), float4 LDS
    {
      const float* wrow = &WbT[j * 516 + c * 64];
      const float* mrow = &memP[c * 64];
      float p1 = 0.f;
#pragma unroll
      for (int i = 0; i < 64; i += 4) {
        float4 wv = *(const float4*)&wrow[i];
        float4 mv = *(const float4*)&mrow[i];
        p1 += wv.x * mv.x + wv.y * mv.y + wv.z * mv.z + wv.w * mv.w;
      }
      parts1P[c * 32 + j] = p1;
    }
    __syncthreads();
    // [2] redA(P) + gelu + tagged storeA(P)
    if (t < 32) {
      float u = xvP;
#pragma unroll
      for (int cc = 0; cc < 8; ++cc) u += parts1P[cc * 32 + t];
      union { float f; unsigned u; } uv; uv.f = gelu_f(u);
      __hip_atomic_store(&gubP[ucol0 + t], tagw | uv.u, __ATOMIC_RELAXED,
                         __HIP_MEMORY_SCOPE_AGENT);
    }
    asm volatile("" ::: "memory");
    // [3] pollB(Q, tag s) -> memQ  (skip s==0: memQ starts zeroed)
    if (s > 0) {
      ull* q = &membQp[t * 2];
      const unsigned ptag = (unsigned)s;
      ull v1, v2;
      for (;;) {
        v1 = __hip_atomic_load(&q[0], __ATOMIC_RELAXED, __HIP_MEMORY_SCOPE_AGENT);
        v2 = __hip_atomic_load(&q[1], __ATOMIC_RELAXED, __HIP_MEMORY_SCOPE_AGENT);
        if (((unsigned)(v1 >> 32) == ptag) & ((unsigned)(v2 >> 32) == ptag)) break;
        __builtin_amdgcn_s_sleep(1);
      }
      union { unsigned u; float f; } m1, m2;
      m1.u = (unsigned)v1; m2.u = (unsigned)v2;
      memQ[t * 2] = m1.f;
      memQ[t * 2 + 1] = m2.f;
    }
    __syncthreads();
    // [4] stage1(Q)
    {
      const float* wrow = &WbT[j * 516 + c * 64];
      const float* mrow = &memQ[c * 64];
      float p1 = 0.f;
#pragma unroll
      for (int i = 0; i < 64; i += 4) {
        float4 wv = *(const float4*)&wrow[i];
        float4 mv = *(const float4*)&mrow[i];
        p1 += wv.x * mv.x + wv.y * mv.y + wv.z * mv.z + wv.w * mv.w;
      }
      parts1Q[c * 32 + j] = p1;
    }
    __syncthreads();
    // [5] redA(Q) + gelu + tagged storeA(Q)
    if (t < 32) {
      float u = xvQ;
#pragma unroll
      for (int cc = 0; cc < 8; ++cc) u += parts1Q[cc * 32 + t];
      union { float f; unsigned u; } uv; uv.f = gelu_f(u);
      __hip_atomic_store(&gubQ[ucol0 + t], tagw | uv.u, __ATOMIC_RELAXED,
                         __HIP_MEMORY_SCOPE_AGENT);
    }
    asm volatile("" ::: "memory");
    // [6] pollA(P) -> guP (4 tagged words per thread)
    {
      ull* p = &gubP[t * 4];
      ull v0, v1, v2, v3;
      for (;;) {
        v0 = __hip_atomic_load(&p[0], __ATOMIC_RELAXED, __HIP_MEMORY_SCOPE_AGENT);
        v1 = __hip_atomic_load(&p[1], __ATOMIC_RELAXED, __HIP_MEMORY_SCOPE_AGENT);
        v2 = __hip_atomic_load(&p[2], __ATOMIC_RELAXED, __HIP_MEMORY_SCOPE_AGENT);
        v3 = __hip_atomic_load(&p[3], __ATOMIC_RELAXED, __HIP_MEMORY_SCOPE_AGENT);
        bool ok = ((unsigned)(v0 >> 32) == utag) & ((unsigned)(v1 >> 32) == utag) &
                  ((unsigned)(v2 >> 32) == utag) & ((unsigned)(v3 >> 32) == utag);
        if (ok) break;
        __builtin_amdgcn_s_sleep(1);
      }
      union { unsigned u; float f; } a0, a1, a2, a3;
      a0.u = (unsigned)v0; a1.u = (unsigned)v1;
      a2.u = (unsigned)v2; a3.u = (unsigned)v3;
      guP[t * 4 + 0] = a0.f;
      guP[t * 4 + 1] = a1.f;
      guP[t * 4 + 2] = a2.f;
      guP[t * 4 + 3] = a3.f;
    }
    // xpart prefetch for next superstep (hidden under stage2 phases)
    float xnP = (t < 32 && s < 2047) ? xpP[(size_t)(s + 1) * 1024 + t] : 0.f;
    float xnQ = (t < 32 && s < 2047) ? xpQ[(size_t)(s + 1) * 1024 + t] : 0.f;
    __syncthreads();
    // [7] stage2(P): full prop for own col (mcol0+dd), u-chunk c2 (64 u)
    {
      const float* wrow = &W2S[dd * 1028 + c2 * 64];
      const float* grow = &guP[c2 * 64];
      float p2 = 0.f;
#pragma unroll
      for (int i = 0; i < 64; i += 4) {
        float4 wv = *(const float4*)&wrow[i];
        float4 gv = *(const float4*)&grow[i];
        p2 += wv.x * gv.x + wv.y * gv.y + wv.z * gv.z + wv.w * gv.w;
      }
      red2P[c2 * 16 + dd] = p2;
    }
    __syncthreads();
    // [8] redB(P): gate + tagged storeB(P)
    if (t < 16) {
      float prop = bt2r;
#pragma unroll
      for (int cc = 0; cc < 16; ++cc) prop += red2P[cc * 16 + t];
      float gate = 1.f / (1.f + __expf(-prop));
      float mnew = memP[mcol0 + t] * (1.f - gate) + prop * gate;
      union { float f; unsigned u; } mv; mv.f = mnew;
      __hip_atomic_store(&membP[mcol0 + t], tagw | mv.u, __ATOMIC_RELAXED,
                         __HIP_MEMORY_SCOPE_AGENT);
    }
    asm volatile("" ::: "memory");
    // [9] pollA(Q) -> guQ
    {
      ull* p = &gubQ[t * 4];
      ull v0, v1, v2, v3;
      for (;;) {
        v0 = __hip_atomic_load(&p[0], __ATOMIC_RELAXED, __HIP_MEMORY_SCOPE_AGENT);
        v1 = __hip_atomic_load(&p[1], __ATOMIC_RELAXED, __HIP_MEMORY_SCOPE_AGENT);
        v2 = __hip_atomic_load(&p[2], __ATOMIC_RELAXED, __HIP_MEMORY_SCOPE_AGENT);
        v3 = __hip_atomic_load(&p[3], __ATOMIC_RELAXED, __HIP_MEMORY_SCOPE_AGENT);
        bool ok = ((unsigned)(v0 >> 32) == utag) & ((unsigned)(v1 >> 32) == utag) &
                  ((unsigned)(v2 >> 32) == utag) & ((unsigned)(v3 >> 32) == utag);
        if (ok) break;
        __builtin_amdgcn_s_sleep(1);
      }
      union { unsigned u; float f; } a0, a1, a2, a3;
      a0.u = (unsigned)v0; a1.u = (unsigned)v1;
      a2.u = (unsigned)v2; a3.u = (unsigned)v3;
      guQ[t * 4 + 0] = a0.f;
      guQ[t * 4 + 1] = a1.f;
      guQ[t * 4 + 2] = a2.f;
      guQ[t * 4 + 3] = a3.f;
    }
    __syncthreads();
    // [10] stage2(Q)
    {
      const float* wrow = &W2S[dd * 1028 + c2 * 64];
      const float* grow = &guQ[c2 * 64];
      float p2 = 0.f;
#pragma unroll
      for (int i = 0; i < 64; i += 4) {
        float4 wv = *(const float4*)&wrow[i];
        float4 gv = *(const float4*)&grow[i];
        p2 += wv.x * gv.x + wv.y * gv.y + wv.z * gv.z + wv.w * gv.w;
      }
      red2Q[c2 * 16 + dd] = p2;
    }
    __syncthreads();
    // [11] redB(Q): gate + tagged storeB(Q)
    if (t < 16) {
      float prop = bt2r;
#pragma unroll
      for (int cc = 0; cc < 16; ++cc) prop += red2Q[cc * 16 + t];
      float gate = 1.f / (1.f + __expf(-prop));
      float mnew = memQ[mcol0 + t] * (1.f - gate) + prop * gate;
      union { float f; unsigned u; } mv; mv.f = mnew;
      __hip_atomic_store(&membQ[mcol0 + t], tagw | mv.u, __ATOMIC_RELAXED,
                         __HIP_MEMORY_SCOPE_AGENT);
    }
    asm volatile("" ::: "memory");
    // [12] pollB(P, s+1) -> memP (for next superstep's stage1(P))
    {
      ull* q = &membP[t * 2];
      ull v1, v2;
      for (;;) {
        v1 = __hip_atomic_load(&q[0], __ATOMIC_RELAXED, __HIP_MEMORY_SCOPE_AGENT);
        v2 = __hip_atomic_load(&q[1], __ATOMIC_RELAXED, __HIP_MEMORY_SCOPE_AGENT);
        if (((unsigned)(v1 >> 32) == utag) & ((unsigned)(v2 >> 32) == utag)) break;
        __builtin_amdgcn_s_sleep(1);
      }
      union { unsigned u; float f; } m1, m2;
      m1.u = (unsigned)v1; m2.u = (unsigned)v2;
      memP[t * 2] = m1.f;
      memP[t * 2 + 1] = m2.f;
    }
    xvP = xnP;
    xvQ = xnQ;
    __syncthreads();
  }

  // final pollB(Q, tag 2048) from slot par = 2047&1 = 1
  {
    ull* membQf = memT + (size_t)(1 * 8 + seqQ) * 512;
    ull* q = &membQf[t * 2];
    const unsigned ftag = 2048u;
    ull v1, v2;
    for (;;) {
      v1 = __hip_atomic_load(&q[0], __ATOMIC_RELAXED, __HIP_MEMORY_SCOPE_AGENT);
      v2 = __hip_atomic_load(&q[1], __ATOMIC_RELAXED, __HIP_MEMORY_SCOPE_AGENT);
      if (((unsigned)(v1 >> 32) == ftag) & ((unsigned)(v2 >> 32) == ftag)) break;
      __builtin_amdgcn_s_sleep(1);
    }
    union { unsigned u; float f; } m1, m2;
    m1.u = (unsigned)v1; m2.u = (unsigned)v2;
    memQ[t * 2] = m1.f;
    memQ[t * 2 + 1] = m2.f;
  }
  __syncthreads();

  if (g == 0 && t < 128) {
    *(float4*)&memfinal[(size_t)seqP * 512 + t * 4] = *(float4*)&memP[t * 4];
    *(float4*)&memfinal[(size_t)seqQ * 512 + t * 4] = *(float4*)&memQ[t * 4];
  }
}

// ---------------- output GEMV ----------------

__global__ __launch_bounds__(256)
void out_gemv_kernel(const float* __restrict__ memf, const float* __restrict__ Wo,
                     const float* __restrict__ bo, float* __restrict__ out) {
  int gid = blockIdx.x * 256 + threadIdx.x;   // 4096 total
  int b = gid >> 9, d = gid & 511;
  const float* mb = memf + (size_t)b * 512;
  float acc = bo[d];
#pragma unroll 8
  for (int k = 0; k < 512; ++k) acc += mb[k] * Wo[(size_t)k * 512 + d];
  out[gid] = acc;
}

// ---------------- launch ----------------

extern "C" void kernel_launch(void* const* d_in, const int* in_sizes, int n_in,
                              void* d_out, int out_size, void* d_ws, size_t ws_size,
                              hipStream_t stream) {
  const float* x   = (const float*)d_in[0];
  const float* Wq  = (const float*)d_in[1];
  const float* bq  = (const float*)d_in[2];
  const float* Wk  = (const float*)d_in[3];
  const float* bk  = (const float*)d_in[4];
  const float* W1  = (const float*)d_in[5];
  const float* b1  = (const float*)d_in[6];
  const float* W2  = (const float*)d_in[7];
  const float* b2  = (const float*)d_in[8];
  const float* lng = (const float*)d_in[9];
  const float* lnb = (const float*)d_in[10];
  const float* Wt1 = (const float*)d_in[11];
  const float* bt1 = (const float*)d_in[12];
  const float* Wt2 = (const float*)d_in[13];
  const float* bt2 = (const float*)d_in[14];
  const float* Wo  = (const float*)d_in[15];
  const float* bo  = (const float*)d_in[16];
  float* out = (float*)d_out;

  char* ws = (char*)d_ws;
  size_t off = 0;
  auto alloc = [&](size_t bytes) -> void* {
    void* p = ws + off;
    off += (bytes + 255) & ~(size_t)255;
    return p;
  };
  float* qk             = (float*)alloc(8ull * 2048 * 64 * 4);
  int* idxb             = (int*)alloc(8ull * 2048 * 4 * 4);
  float* gathf          = (float*)alloc(16384ull * 512 * 4);
  unsigned short* gathb = (unsigned short*)alloc(16384ull * 512 * 2);
  unsigned short* h1b   = (unsigned short*)alloc(16384ull * 1024 * 2);
  float* ypre           = (float*)alloc(16384ull * 512 * 4);
  unsigned short* yb    = (unsigned short*)alloc(16384ull * 512 * 2);
  float* xpart          = (float*)alloc(16384ull * 1024 * 4);
  unsigned short* w1t   = (unsigned short*)alloc(1024ull * 512 * 2);
  unsigned short* w2t   = (unsigned short*)alloc(512ull * 1024 * 2);
  unsigned short* wt1t  = (unsigned short*)alloc(1024ull * 512 * 2);
  float* wt2t           = (float*)alloc(512ull * 1024 * 4);      // Wt2^T fp32
  float* wqkb           = (float*)alloc(512ull * 64 * 4);
  ull* guT              = (ull*)alloc(2ull * 8 * 1024 * 8);      // 128 KB
  ull* memT             = (ull*)alloc(2ull * 8 * 512 * 8);       // 64 KB
  float* memf           = (float*)alloc(8ull * 512 * 4);
  if (off > ws_size) return;  // workspace too small -> visible bench failure

  wqk_kernel<<<128, 256, 0, stream>>>(Wq, Wk, wqkb);
  transpose_bf16_kernel<<<dim3(16, 32), 256, 0, stream>>>(W1, w1t, 512, 1024);
  transpose_bf16_kernel<<<dim3(32, 16), 256, 0, stream>>>(W2, w2t, 1024, 512);
  transpose_bf16_kernel<<<dim3(16, 32), 256, 0, stream>>>(Wt1, wt1t, 512, 1024);
  transpose_f32_kernel<<<dim3(32, 16), 256, 0, stream>>>(Wt2, wt2t, 1024, 512);

  qk_kernel<<<1024, 256, 0, stream>>>(x, wqkb, bq, bk, qk);
  topk_kernel<<<1024, 256, 0, stream>>>(qk, idxb);
  gather_kernel<<<16384, 128, 0, stream>>>(x, idxb, gathf, gathb);

  gemm_bf16_k<0><<<dim3(128, 8), 256, 0, stream>>>(gathb, w1t, b1, nullptr, h1b,
                                                   16384, 1024, 512);
  gemm_bf16_k<1><<<dim3(128, 4), 256, 0, stream>>>(h1b, w2t, b2, gathf, ypre,
                                                   16384, 512, 1024);
  ln_kernel<<<16384, 128, 0, stream>>>(ypre, lng, lnb, yb);
  gemm_bf16_k<2><<<dim3(128, 8), 256, 0, stream>>>(yb, wt1t, bt1, nullptr, xpart,
                                                   16384, 1024, 512);

  system2_kernel<<<128, 256, 0, stream>>>(Wt1, wt2t, bt2, xpart, guT, memT,
                                          memf);
  out_gemv_kernel<<<16, 256, 0, stream>>>(memf, Wo, bo, out);
}

// Round 6
// 9472.299 us; speedup vs baseline: 2.6328x; 1.0659x over previous
//
#include <hip/hip_runtime.h>
#include <math.h>
#include <stdint.h>

// ---------------------------------------------------------------------------
// InvertedCognitionModel: B=8, T=2048, D=512, KQ=32, K=4
//   router (fp32 sim + top4, fused) -> gather-mean -> FFN+LN (bf16 MFMA)
//   -> serial gated memory scan: 4 teams x 32 WGs, 2 sequences interleaved,
//      tagged-LLC sync + SPECULATIVE EARLY POLL LOADS + LDS-only barriers
//   -> output GEMV
// ---------------------------------------------------------------------------

using bf16x8 = __attribute__((ext_vector_type(8))) short;
using f32x4v = __attribute__((ext_vector_type(4))) float;
typedef unsigned long long ull;

__device__ inline unsigned short f2b(float f) {
  union { float f; unsigned int u; } v; v.f = f;
  unsigned int r = v.u + 0x7fffu + ((v.u >> 16) & 1u);   // RNE
  return (unsigned short)(r >> 16);
}

__device__ inline float gelu_f(float x) {
  return 0.5f * x * (1.0f + erff(x * 0.70710678118654752f));
}

// LDS-ordering-only barrier: drains LDS (lgkmcnt) but leaves global loads
// and stores IN FLIGHT across the barrier (HK counted-wait idiom). The
// tagged-word protocol tolerates any global reordering (stale tag -> retry),
// so vmcnt(0) drains -- which hipcc emits before every __syncthreads() and
// which charged ~900cy store-ACK + full poll flights to each barrier -- are
// unnecessary in the scan loop.
__device__ inline void bar_lds() {
  asm volatile("s_waitcnt lgkmcnt(0)" ::: "memory");
  __builtin_amdgcn_s_barrier();
}

// sorted-descending top-4 insert, tie-break lower index first
__device__ inline void ins4(float v, int i,
                            float& v0, int& i0, float& v1, int& i1,
                            float& v2, int& i2, float& v3, int& i3) {
  bool b0 = (v > v0) || (v == v0 && i < i0);
  bool b1 = (v > v1) || (v == v1 && i < i1);
  bool b2 = (v > v2) || (v == v2 && i < i2);
  bool b3 = (v > v3) || (v == v3 && i < i3);
  float nv3 = b2 ? v2 : (b3 ? v : v3); int ni3 = b2 ? i2 : (b3 ? i : i3);
  float nv2 = b1 ? v1 : (b2 ? v : v2); int ni2 = b1 ? i1 : (b2 ? i : i2);
  float nv1 = b0 ? v0 : (b1 ? v : v1); int ni1 = b0 ? i0 : (b1 ? i : i1);
  float nv0 = b0 ? v  : v0;            int ni0 = b0 ? i  : i0;
  v0=nv0; i0=ni0; v1=nv1; i1=ni1; v2=nv2; i2=ni2; v3=nv3; i3=ni3;
}

// ---------------- prep kernels ----------------

__global__ __launch_bounds__(256)
void wqk_kernel(const float* __restrict__ Wq, const float* __restrict__ Wk,
                float* __restrict__ wqk) {
  int id = blockIdx.x * 256 + threadIdx.x;        // < 512*64
  int d = id >> 6, c = id & 63;
  wqk[id] = (c < 32) ? Wq[d * 32 + c] : Wk[d * 32 + (c - 32)];
}

// dst[n][k] = bf16(src[k][n]); src is [>=K x N] row-major, dst [N x K]
__global__ __launch_bounds__(256)
void transpose_bf16_kernel(const float* __restrict__ src,
                           unsigned short* __restrict__ dst, int K, int N) {
  __shared__ float tile[32][33];
  int bk = blockIdx.x << 5, bn = blockIdx.y << 5;
  int c = threadIdx.x & 31, r8 = threadIdx.x >> 5;
  for (int r = r8; r < 32; r += 8) tile[r][c] = src[(size_t)(bk + r) * N + bn + c];
  __syncthreads();
  for (int r = r8; r < 32; r += 8) dst[(size_t)(bn + r) * K + bk + c] = f2b(tile[c][r]);
}

// dst[n][k] = src[k][n] (fp32), for coalesced LDS staging of Wt2 columns
__global__ __launch_bounds__(256)
void transpose_f32_kernel(const float* __restrict__ src,
                          float* __restrict__ dst, int K, int N) {
  __shared__ float tile[32][33];
  int bk = blockIdx.x << 5, bn = blockIdx.y << 5;
  int c = threadIdx.x & 31, r8 = threadIdx.x >> 5;
  for (int r = r8; r < 32; r += 8) tile[r][c] = src[(size_t)(bk + r) * N + bn + c];
  __syncthreads();
  for (int r = r8; r < 32; r += 8) dst[(size_t)(bn + r) * K + bk + c] = tile[c][r];
}

// ---------------- router ----------------

// q|k projection: qkout[b,t,0:32]=q, [32:64]=k (fp32, biases included)
__global__ __launch_bounds__(256)
void qk_kernel(const float* __restrict__ x, const float* __restrict__ wqk,
               const float* __restrict__ bq, const float* __restrict__ bk,
               float* __restrict__ qkout) {
  __shared__ float xs[16][512];
  int tid = threadIdx.x;
  int b = blockIdx.x >> 7;
  int t0 = (blockIdx.x & 127) << 4;
  const float* xb = x + ((size_t)(b * 2048 + t0)) * 512;
#pragma unroll
  for (int i = 0; i < 8; ++i) {
    int f = i * 256 + tid;
    int r = f >> 7, c4 = f & 127;
    *(float4*)&xs[r][c4 * 4] = *(const float4*)&xb[(size_t)r * 512 + c4 * 4];
  }
  __syncthreads();
  int c = tid & 63, r4 = tid >> 6;
  float a0 = 0.f, a1 = 0.f, a2 = 0.f, a3 = 0.f;
#pragma unroll 4
  for (int d = 0; d < 512; ++d) {
    float w = wqk[d * 64 + c];
    a0 += xs[r4][d] * w;
    a1 += xs[r4 + 4][d] * w;
    a2 += xs[r4 + 8][d] * w;
    a3 += xs[r4 + 12][d] * w;
  }
  float bias = (c < 32) ? bq[c] : bk[c - 32];
  size_t base = ((size_t)(b * 2048 + t0)) * 64 + c;
  qkout[base + (size_t)r4 * 64] = a0 + bias;
  qkout[base + (size_t)(r4 + 4) * 64] = a1 + bias;
  qkout[base + (size_t)(r4 + 8) * 64] = a2 + bias;
  qkout[base + (size_t)(r4 + 12) * 64] = a3 + bias;
}

// fused sim + top-4: block = 16 query rows; never materializes sim
__global__ __launch_bounds__(256)
void topk_kernel(const float* __restrict__ qkb, int* __restrict__ idxout) {
  __shared__ float qs[16][36];
  __shared__ float ks[128][36];
  __shared__ float mv[16][16][4];
  __shared__ int   mi[16][16][4];
  int tid = threadIdx.x;
  int b = blockIdx.x >> 7;
  int t0 = (blockIdx.x & 127) << 4;
  const float* qb = qkb + ((size_t)b * 2048) * 64;
  if (tid < 128) {
    int r = tid >> 3, c4 = tid & 7;
    *(float4*)&qs[r][c4 * 4] = *(const float4*)&qb[(size_t)(t0 + r) * 64 + c4 * 4];
  }
  __syncthreads();
  int tl = tid >> 4, sl = tid & 15;
  float qv[32];
#pragma unroll
  for (int kk = 0; kk < 32; ++kk) qv[kk] = qs[tl][kk];
  float v0 = -INFINITY, v1 = -INFINITY, v2 = -INFINITY, v3 = -INFINITY;
  int i0 = 0x7fffffff, i1 = 0x7fffffff, i2 = 0x7fffffff, i3 = 0x7fffffff;
  for (int s0 = 0; s0 < 2048; s0 += 128) {
    __syncthreads();
#pragma unroll
    for (int p = 0; p < 4; ++p) {
      int f = p * 256 + tid;
      int r = f >> 3, c4 = f & 7;
      *(float4*)&ks[r][c4 * 4] =
          *(const float4*)&qb[(size_t)(s0 + r) * 64 + 32 + c4 * 4];
    }
    __syncthreads();
#pragma unroll
    for (int j = 0; j < 8; ++j) {
      int srow = j * 16 + sl;
      float accv = 0.f;
#pragma unroll
      for (int k4 = 0; k4 < 8; ++k4) {
        float4 kv = *(const float4*)&ks[srow][k4 * 4];
        accv += qv[k4 * 4 + 0] * kv.x + qv[k4 * 4 + 1] * kv.y +
                qv[k4 * 4 + 2] * kv.z + qv[k4 * 4 + 3] * kv.w;
      }
      ins4(accv, s0 + srow, v0, i0, v1, i1, v2, i2, v3, i3);
    }
  }
  mv[tl][sl][0] = v0; mv[tl][sl][1] = v1; mv[tl][sl][2] = v2; mv[tl][sl][3] = v3;
  mi[tl][sl][0] = i0; mi[tl][sl][1] = i1; mi[tl][sl][2] = i2; mi[tl][sl][3] = i3;
  __syncthreads();
  if (tid < 16) {
    float w0 = -INFINITY, w1 = -INFINITY, w2 = -INFINITY, w3 = -INFINITY;
    int a0 = 0x7fffffff, a1 = 0x7fffffff, a2 = 0x7fffffff, a3 = 0x7fffffff;
    for (int ss = 0; ss < 16; ++ss)
#pragma unroll
      for (int q = 0; q < 4; ++q)
        ins4(mv[tid][ss][q], mi[tid][ss][q], w0, a0, w1, a1, w2, a2, w3, a3);
    int4 o; o.x = a0; o.y = a1; o.z = a2; o.w = a3;
    *(int4*)&idxout[((size_t)(b * 2048 + t0 + tid)) * 4] = o;
  }
}

__global__ __launch_bounds__(128)
void gather_kernel(const float* __restrict__ x, const int* __restrict__ idx,
                   float* __restrict__ gf, unsigned short* __restrict__ gb) {
  int bt = blockIdx.x;
  int b = bt >> 11;
  const int4 iv = *(const int4*)&idx[(size_t)bt * 4];
  int tid = threadIdx.x;
  const float* xb = x + ((size_t)b * 2048) * 512;
  float4 p0 = *(const float4*)&xb[(size_t)iv.x * 512 + tid * 4];
  float4 p1 = *(const float4*)&xb[(size_t)iv.y * 512 + tid * 4];
  float4 p2 = *(const float4*)&xb[(size_t)iv.z * 512 + tid * 4];
  float4 p3 = *(const float4*)&xb[(size_t)iv.w * 512 + tid * 4];
  float4 m;
  m.x = (p0.x + p1.x + p2.x + p3.x) * 0.25f;
  m.y = (p0.y + p1.y + p2.y + p3.y) * 0.25f;
  m.z = (p0.z + p1.z + p2.z + p3.z) * 0.25f;
  m.w = (p0.w + p1.w + p2.w + p3.w) * 0.25f;
  *(float4*)&gf[(size_t)bt * 512 + tid * 4] = m;
  ushort4 u; u.x = f2b(m.x); u.y = f2b(m.y); u.z = f2b(m.z); u.w = f2b(m.w);
  *(ushort4*)&gb[(size_t)bt * 512 + tid * 4] = u;
}

// ---------------- MFMA GEMM: C = A[MxK] * Bt[NxK]^T (+bias, epilogues) ------
// MODE 0: out bf16 = gelu(acc+bias)   MODE 1: out f32 = acc+bias+resid
// MODE 2: out f32 = acc+bias

template <int MODE>
__global__ __launch_bounds__(256, 2)
void gemm_bf16_k(const unsigned short* __restrict__ A,
                 const unsigned short* __restrict__ Bt,
                 const float* __restrict__ bias,
                 const float* __restrict__ resid,
                 void* __restrict__ outp, int M, int N, int K) {
  __shared__ unsigned short sA[128 * 32];
  __shared__ unsigned short sB[128 * 32];
  const int tid = threadIdx.x;
  const int lane = tid & 63, wave = tid >> 6;
  const int m0 = blockIdx.x * 128, n0 = blockIdx.y * 128;
  const int col16 = lane & 15, quad = lane >> 4;
  const int wm = wave >> 1, wn = wave & 1;
  f32x4v acc[4][4];
#pragma unroll
  for (int i = 0; i < 4; ++i)
#pragma unroll
    for (int j = 0; j < 4; ++j) {
      f32x4v z = {0.f, 0.f, 0.f, 0.f};
      acc[i][j] = z;
    }
  const int nkt = K >> 5;
  for (int kt = 0; kt < nkt; ++kt) {
    const int k0 = kt << 5;
#pragma unroll
    for (int p = 0; p < 2; ++p) {
      int f = p * 256 + tid;
      int row = f >> 2, q4 = f & 3;
      *(uint4*)&sA[row * 32 + q4 * 8] =
          *(const uint4*)(A + (size_t)(m0 + row) * K + k0 + q4 * 8);
      *(uint4*)&sB[row * 32 + q4 * 8] =
          *(const uint4*)(Bt + (size_t)(n0 + row) * K + k0 + q4 * 8);
    }
    __syncthreads();
    bf16x8 af[4], bfr[4];
#pragma unroll
    for (int i = 0; i < 4; ++i)
      af[i] = *(const bf16x8*)&sA[(wm * 64 + i * 16 + col16) * 32 + quad * 8];
#pragma unroll
    for (int j = 0; j < 4; ++j)
      bfr[j] = *(const bf16x8*)&sB[(wn * 64 + j * 16 + col16) * 32 + quad * 8];
#pragma unroll
    for (int i = 0; i < 4; ++i)
#pragma unroll
      for (int j = 0; j < 4; ++j)
        acc[i][j] = __builtin_amdgcn_mfma_f32_16x16x32_bf16(af[i], bfr[j],
                                                            acc[i][j], 0, 0, 0);
    __syncthreads();
  }
  float* outf = (float*)outp;
  unsigned short* outb = (unsigned short*)outp;
#pragma unroll
  for (int i = 0; i < 4; ++i)
#pragma unroll
    for (int j = 0; j < 4; ++j) {
      int col = n0 + wn * 64 + j * 16 + col16;
      float bs = bias[col];
#pragma unroll
      for (int r = 0; r < 4; ++r) {
        int row = m0 + wm * 64 + i * 16 + quad * 4 + r;
        float v = acc[i][j][r] + bs;
        if (MODE == 0) {
          outb[(size_t)row * N + col] = f2b(gelu_f(v));
        } else if (MODE == 1) {
          outf[(size_t)row * N + col] = v + resid[(size_t)row * N + col];
        } else {
          outf[(size_t)row * N + col] = v;
        }
      }
    }
}

// ---------------- LayerNorm (row-wise, fp32 -> bf16) ----------------

__global__ __launch_bounds__(128)
void ln_kernel(const float* __restrict__ ypre, const float* __restrict__ lg,
               const float* __restrict__ lb, unsigned short* __restrict__ yb) {
  int row = blockIdx.x, tid = threadIdx.x;
  float4 v = *(const float4*)&ypre[(size_t)row * 512 + tid * 4];
  float s = v.x + v.y + v.z + v.w;
  float sq = v.x * v.x + v.y * v.y + v.z * v.z + v.w * v.w;
#pragma unroll
  for (int off = 1; off < 64; off <<= 1) {
    s += __shfl_xor(s, off, 64);
    sq += __shfl_xor(sq, off, 64);
  }
  __shared__ float red[4];
  if ((tid & 63) == 0) { red[(tid >> 6) * 2] = s; red[(tid >> 6) * 2 + 1] = sq; }
  __syncthreads();
  float S = red[0] + red[2], SQ = red[1] + red[3];
  float mu = S * (1.f / 512.f);
  float var = SQ * (1.f / 512.f) - mu * mu;
  float rstd = rsqrtf(var + 1e-5f);
  float4 g4 = *(const float4*)&lg[tid * 4];
  float4 b4 = *(const float4*)&lb[tid * 4];
  ushort4 u;
  u.x = f2b((v.x - mu) * rstd * g4.x + b4.x);
  u.y = f2b((v.y - mu) * rstd * g4.y + b4.y);
  u.z = f2b((v.z - mu) * rstd * g4.z + b4.z);
  u.w = f2b((v.w - mu) * rstd * g4.w + b4.w);
  *(ushort4*)&yb[(size_t)row * 512 + tid * 4] = u;
}

// ---------------- System2: persistent serial scan, 2-way interleaved -------
// 4 teams x 32 WGs x 256 thr; blockIdx = g*4 + team. Sequences P = team*2,
// Q = team*2+1 interleaved (R5 structure, validated: per-step 4.25->2.40us).
//
// R6 changes (attack the exposed latency R5 left on the critical path):
//  (a) SPECULATIVE EARLY POLL LOADS: each exchange's atomic loads are issued
//      BEFORE the covering compute phase (pinned by asm memory clobbers);
//      tags are checked at the consume point; mismatch -> normal poll loop.
//      The tagged protocol is order-tolerant, so early loads merely retry.
//  (b) LDS-ONLY BARRIERS (bar_lds = s_waitcnt lgkmcnt(0) + raw s_barrier)
//      in the scan loop: hipcc's __syncthreads() emits s_waitcnt vmcnt(0)
//      before s_barrier, charging every tagged store's ~900cy LLC ACK and
//      every poll's full flight to the barrier. All intra-WG dataflow is
//      LDS, so lgkmcnt(0) suffices; global ops stay in flight (HK T3/T4
//      idiom). Same-WG global producer->consumer may read stale -> tag
//      check retries; stores drain unconditionally -> no liveness issue.
//
// SYNC (unchanged R2 protocol): tagged words (tag<<32)|float_bits, tag=s+1,
// relaxed agent-scope 8B atomics (single-copy atomic -> tag rides with
// payload), parity double-buffer per sequence; monotone tags vs stale/0xAA
// poison. Overwrite safety: any slot overwrite 2 supersteps later is gated
// through a poll that transitively requires all WGs past the reading phase.

__global__ __launch_bounds__(256)
void system2_kernel(const float* __restrict__ Wt1, const float* __restrict__ Wt2T,
                    const float* __restrict__ bt2, const float* __restrict__ xpart,
                    ull* __restrict__ guT, ull* __restrict__ memT,
                    float* __restrict__ memfinal) {
  __shared__ float WbT[32 * 516];    // stage1 W [j][k], stride 516 (66048 B)
  __shared__ float W2S[16 * 1028];   // stage2 W [dd][u], stride 1028 (65792 B)
  __shared__ float memP[512], memQ[512];
  __shared__ float guP[1024], guQ[1024];
  __shared__ float parts1P[256], parts1Q[256];
  __shared__ float red2P[256], red2Q[256];

  const int t = threadIdx.x;
  const int team = blockIdx.x & 3;        // 0..3
  const int g = blockIdx.x >> 2;          // 0..31
  const int seqP = team * 2, seqQ = team * 2 + 1;
  const int ucol0 = g << 5;
  const int mcol0 = g << 4;

  // ---- load weights into LDS (one-time) ----
  for (int idx = t; idx < 32 * 512; idx += 256) {
    int j = idx & 31, k = idx >> 5;
    WbT[j * 516 + k] = Wt1[(size_t)(512 + k) * 1024 + ucol0 + j];
  }
  for (int idx = t; idx < 16 * 1024; idx += 256) {
    int dd = idx >> 10, u = idx & 1023;
    W2S[dd * 1028 + u] = Wt2T[(size_t)(mcol0 + dd) * 1024 + u];
  }
  memP[t] = 0.f; memP[t + 256] = 0.f;
  memQ[t] = 0.f; memQ[t + 256] = 0.f;
  const float bt2r = (t < 16) ? bt2[mcol0 + t] : 0.f;
  __syncthreads();

  const int j = t & 31, c = t >> 5;        // stage1 roles: col j, k-chunk c(8)
  const int dd = t & 15, c2 = t >> 4;      // stage2 roles: col dd, u-chunk c2(16)
  const float* xpP = xpart + (size_t)seqP * 2048 * 1024 + ucol0;
  const float* xpQ = xpart + (size_t)seqQ * 2048 * 1024 + ucol0;
  float xvP = (t < 32) ? xpP[t] : 0.f;
  float xvQ = (t < 32) ? xpQ[t] : 0.f;

  for (int s = 0; s < 2048; ++s) {
    const int par = s & 1;
    ull* gubP = guT + (size_t)(par * 8 + seqP) * 1024;
    ull* gubQ = guT + (size_t)(par * 8 + seqQ) * 1024;
    ull* membP = memT + (size_t)(par * 8 + seqP) * 512;
    ull* membQ = memT + (size_t)(par * 8 + seqQ) * 512;
    ull* membQp = memT + (size_t)(((s + 1) & 1) * 8 + seqQ) * 512;  // tag s slot
    const unsigned utag = (unsigned)(s + 1);
    const ull tagw = ((ull)utag) << 32;

    // EARLY-ISSUE 0: memQ poll loads (tag s; stored prev superstep [11]) and
    // next-step xpart prefetch. Covered by stage1(P).
    ull eqm1 = 0, eqm2 = 0;
    if (s > 0) {
      eqm1 = __hip_atomic_load(&membQp[t * 2], __ATOMIC_RELAXED,
                               __HIP_MEMORY_SCOPE_AGENT);
      eqm2 = __hip_atomic_load(&membQp[t * 2 + 1], __ATOMIC_RELAXED,
                               __HIP_MEMORY_SCOPE_AGENT);
    }
    float xnP = (t < 32 && s < 2047) ? xpP[(size_t)(s + 1) * 1024 + t] : 0.f;
    float xnQ = (t < 32 && s < 2047) ? xpQ[(size_t)(s + 1) * 1024 + t] : 0.f;
    asm volatile("" ::: "memory");

    // [1] stage1(P): parts over k-chunk c (64 k), float4 LDS
    {
      const float* wrow = &WbT[j * 516 + c * 64];
      const float* mrow = &memP[c * 64];
      float p1 = 0.f;
#pragma unroll
      for (int i = 0; i < 64; i += 4) {
        float4 wv = *(const float4*)&wrow[i];
        float4 mv = *(const float4*)&mrow[i];
        p1 += wv.x * mv.x + wv.y * mv.y + wv.z * mv.z + wv.w * mv.w;
      }
      parts1P[c * 32 + j] = p1;
    }
    bar_lds();
    // [2] redA(P) + gelu + tagged storeA(P)
    if (t < 32) {
      float u = xvP;
#pragma unroll
      for (int cc = 0; cc < 8; ++cc) u += parts1P[cc * 32 + t];
      union { float f; unsigned u; } uv; uv.f = gelu_f(u);
      __hip_atomic_store(&gubP[ucol0 + t], tagw | uv.u, __ATOMIC_RELAXED,
                         __HIP_MEMORY_SCOPE_AGENT);
    }
    asm volatile("" ::: "memory");
    // [3'] consume memQ (tag s): check early values, fallback poll on miss
    if (s > 0) {
      const unsigned ptag = (unsigned)s;
      if (((unsigned)(eqm1 >> 32) != ptag) | ((unsigned)(eqm2 >> 32) != ptag)) {
        ull* q = &membQp[t * 2];
        for (;;) {
          eqm1 = __hip_atomic_load(&q[0], __ATOMIC_RELAXED, __HIP_MEMORY_SCOPE_AGENT);
          eqm2 = __hip_atomic_load(&q[1], __ATOMIC_RELAXED, __HIP_MEMORY_SCOPE_AGENT);
          if (((unsigned)(eqm1 >> 32) == ptag) & ((unsigned)(eqm2 >> 32) == ptag)) break;
          __builtin_amdgcn_s_sleep(1);
        }
      }
      union { unsigned u; float f; } m1, m2;
      m1.u = (unsigned)eqm1; m2.u = (unsigned)eqm2;
      memQ[t * 2] = m1.f;
      memQ[t * 2 + 1] = m2.f;
    }
    bar_lds();

    // EARLY-ISSUE 1: guP poll loads (stored at [2]); covered by [4]+[5]
    ull ep0, ep1, ep2, ep3;
    {
      ull* p = &gubP[t * 4];
      ep0 = __hip_atomic_load(&p[0], __ATOMIC_RELAXED, __HIP_MEMORY_SCOPE_AGENT);
      ep1 = __hip_atomic_load(&p[1], __ATOMIC_RELAXED, __HIP_MEMORY_SCOPE_AGENT);
      ep2 = __hip_atomic_load(&p[2], __ATOMIC_RELAXED, __HIP_MEMORY_SCOPE_AGENT);
      ep3 = __hip_atomic_load(&p[3], __ATOMIC_RELAXED, __HIP_MEMORY_SCOPE_AGENT);
    }
    asm volatile("" ::: "memory");
    // [4] stage1(Q)
    {
      const float* wrow = &WbT[j * 516 + c * 64];
      const float* mrow = &memQ[c * 64];
      float p1 = 0.f;
#pragma unroll
      for (int i = 0; i < 64; i += 4) {
        float4 wv = *(const float4*)&wrow[i];
        float4 mv = *(const float4*)&mrow[i];
        p1 += wv.x * mv.x + wv.y * mv.y + wv.z * mv.z + wv.w * mv.w;
      }
      parts1Q[c * 32 + j] = p1;
    }
    bar_lds();
    // [5] redA(Q) + gelu + tagged storeA(Q)
    if (t < 32) {
      float u = xvQ;
#pragma unroll
      for (int cc = 0; cc < 8; ++cc) u += parts1Q[cc * 32 + t];
      union { float f; unsigned u; } uv; uv.f = gelu_f(u);
      __hip_atomic_store(&gubQ[ucol0 + t], tagw | uv.u, __ATOMIC_RELAXED,
                         __HIP_MEMORY_SCOPE_AGENT);
    }
    asm volatile("" ::: "memory");
    // [6'] consume guP: check early values, fallback poll on miss
    {
      bool ok = ((unsigned)(ep0 >> 32) == utag) & ((unsigned)(ep1 >> 32) == utag) &
                ((unsigned)(ep2 >> 32) == utag) & ((unsigned)(ep3 >> 32) == utag);
      if (!ok) {
        ull* p = &gubP[t * 4];
        for (;;) {
          ep0 = __hip_atomic_load(&p[0], __ATOMIC_RELAXED, __HIP_MEMORY_SCOPE_AGENT);
          ep1 = __hip_atomic_load(&p[1], __ATOMIC_RELAXED, __HIP_MEMORY_SCOPE_AGENT);
          ep2 = __hip_atomic_load(&p[2], __ATOMIC_RELAXED, __HIP_MEMORY_SCOPE_AGENT);
          ep3 = __hip_atomic_load(&p[3], __ATOMIC_RELAXED, __HIP_MEMORY_SCOPE_AGENT);
          ok = ((unsigned)(ep0 >> 32) == utag) & ((unsigned)(ep1 >> 32) == utag) &
               ((unsigned)(ep2 >> 32) == utag) & ((unsigned)(ep3 >> 32) == utag);
          if (ok) break;
          __builtin_amdgcn_s_sleep(1);
        }
      }
      union { unsigned u; float f; } a0, a1, a2, a3;
      a0.u = (unsigned)ep0; a1.u = (unsigned)ep1;
      a2.u = (unsigned)ep2; a3.u = (unsigned)ep3;
      guP[t * 4 + 0] = a0.f;
      guP[t * 4 + 1] = a1.f;
      guP[t * 4 + 2] = a2.f;
      guP[t * 4 + 3] = a3.f;
    }
    bar_lds();

    // EARLY-ISSUE 2: guQ poll loads (stored at [5]); covered by [7]+[8]
    ull eq0, eq1, eq2, eq3;
    {
      ull* p = &gubQ[t * 4];
      eq0 = __hip_atomic_load(&p[0], __ATOMIC_RELAXED, __HIP_MEMORY_SCOPE_AGENT);
      eq1 = __hip_atomic_load(&p[1], __ATOMIC_RELAXED, __HIP_MEMORY_SCOPE_AGENT);
      eq2 = __hip_atomic_load(&p[2], __ATOMIC_RELAXED, __HIP_MEMORY_SCOPE_AGENT);
      eq3 = __hip_atomic_load(&p[3], __ATOMIC_RELAXED, __HIP_MEMORY_SCOPE_AGENT);
    }
    asm volatile("" ::: "memory");
    // [7] stage2(P): full prop for own col (mcol0+dd), u-chunk c2 (64 u)
    {
      const float* wrow = &W2S[dd * 1028 + c2 * 64];
      const float* grow = &guP[c2 * 64];
      float p2 = 0.f;
#pragma unroll
      for (int i = 0; i < 64; i += 4) {
        float4 wv = *(const float4*)&wrow[i];
        float4 gv = *(const float4*)&grow[i];
        p2 += wv.x * gv.x + wv.y * gv.y + wv.z * gv.z + wv.w * gv.w;
      }
      red2P[c2 * 16 + dd] = p2;
    }
    bar_lds();
    // [8] redB(P): gate + tagged storeB(P)
    if (t < 16) {
      float prop = bt2r;
#pragma unroll
      for (int cc = 0; cc < 16; ++cc) prop += red2P[cc * 16 + t];
      float gate = 1.f / (1.f + __expf(-prop));
      float mnew = memP[mcol0 + t] * (1.f - gate) + prop * gate;
      union { float f; unsigned u; } mv; mv.f = mnew;
      __hip_atomic_store(&membP[mcol0 + t], tagw | mv.u, __ATOMIC_RELAXED,
                         __HIP_MEMORY_SCOPE_AGENT);
    }
    asm volatile("" ::: "memory");
    // [9'] consume guQ: check early values, fallback poll on miss
    {
      bool ok = ((unsigned)(eq0 >> 32) == utag) & ((unsigned)(eq1 >> 32) == utag) &
                ((unsigned)(eq2 >> 32) == utag) & ((unsigned)(eq3 >> 32) == utag);
      if (!ok) {
        ull* p = &gubQ[t * 4];
        for (;;) {
          eq0 = __hip_atomic_load(&p[0], __ATOMIC_RELAXED, __HIP_MEMORY_SCOPE_AGENT);
          eq1 = __hip_atomic_load(&p[1], __ATOMIC_RELAXED, __HIP_MEMORY_SCOPE_AGENT);
          eq2 = __hip_atomic_load(&p[2], __ATOMIC_RELAXED, __HIP_MEMORY_SCOPE_AGENT);
          eq3 = __hip_atomic_load(&p[3], __ATOMIC_RELAXED, __HIP_MEMORY_SCOPE_AGENT);
          ok = ((unsigned)(eq0 >> 32) == utag) & ((unsigned)(eq1 >> 32) == utag) &
               ((unsigned)(eq2 >> 32) == utag) & ((unsigned)(eq3 >> 32) == utag);
          if (ok) break;
          __builtin_amdgcn_s_sleep(1);
        }
      }
      union { unsigned u; float f; } a0, a1, a2, a3;
      a0.u = (unsigned)eq0; a1.u = (unsigned)eq1;
      a2.u = (unsigned)eq2; a3.u = (unsigned)eq3;
      guQ[t * 4 + 0] = a0.f;
      guQ[t * 4 + 1] = a1.f;
      guQ[t * 4 + 2] = a2.f;
      guQ[t * 4 + 3] = a3.f;
    }
    bar_lds();

    // EARLY-ISSUE 3: memP poll loads (tag s+1; stored at [8]); covered by [10]+[11]
    ull em1, em2;
    {
      em1 = __hip_atomic_load(&membP[t * 2], __ATOMIC_RELAXED,
                              __HIP_MEMORY_SCOPE_AGENT);
      em2 = __hip_atomic_load(&membP[t * 2 + 1], __ATOMIC_RELAXED,
                              __HIP_MEMORY_SCOPE_AGENT);
    }
    asm volatile("" ::: "memory");
    // [10] stage2(Q)
    {
      const float* wrow = &W2S[dd * 1028 + c2 * 64];
      const float* grow = &guQ[c2 * 64];
      float p2 = 0.f;
#pragma unroll
      for (int i = 0; i < 64; i += 4) {
        float4 wv = *(const float4*)&wrow[i];
        float4 gv = *(const float4*)&grow[i];
        p2 += wv.x * gv.x + wv.y * gv.y + wv.z * gv.z + wv.w * gv.w;
      }
      red2Q[c2 * 16 + dd] = p2;
    }
    bar_lds();
    // [11] redB(Q): gate + tagged storeB(Q)
    if (t < 16) {
      float prop = bt2r;
#pragma unroll
      for (int cc = 0; cc < 16; ++cc) prop += red2Q[cc * 16 + t];
      float gate = 1.f / (1.f + __expf(-prop));
      float mnew = memQ[mcol0 + t] * (1.f - gate) + prop * gate;
      union { float f; unsigned u; } mv; mv.f = mnew;
      __hip_atomic_store(&membQ[mcol0 + t], tagw | mv.u, __ATOMIC_RELAXED,
                         __HIP_MEMORY_SCOPE_AGENT);
    }
    asm volatile("" ::: "memory");
    // [12'] consume memP (tag s+1): check early values, fallback poll
    {
      if (((unsigned)(em1 >> 32) != utag) | ((unsigned)(em2 >> 32) != utag)) {
        ull* q = &membP[t * 2];
        for (;;) {
          em1 = __hip_atomic_load(&q[0], __ATOMIC_RELAXED, __HIP_MEMORY_SCOPE_AGENT);
          em2 = __hip_atomic_load(&q[1], __ATOMIC_RELAXED, __HIP_MEMORY_SCOPE_AGENT);
          if (((unsigned)(em1 >> 32) == utag) & ((unsigned)(em2 >> 32) == utag)) break;
          __builtin_amdgcn_s_sleep(1);
        }
      }
      union { unsigned u; float f; } m1, m2;
      m1.u = (unsigned)em1; m2.u = (unsigned)em2;
      memP[t * 2] = m1.f;
      memP[t * 2 + 1] = m2.f;
    }
    xvP = xnP;
    xvQ = xnQ;
    bar_lds();
  }

  // final pollB(Q, tag 2048) from slot par = 2047&1 = 1
  {
    ull* membQf = memT + (size_t)(1 * 8 + seqQ) * 512;
    ull* q = &membQf[t * 2];
    const unsigned ftag = 2048u;
    ull v1, v2;
    for (;;) {
      v1 = __hip_atomic_load(&q[0], __ATOMIC_RELAXED, __HIP_MEMORY_SCOPE_AGENT);
      v2 = __hip_atomic_load(&q[1], __ATOMIC_RELAXED, __HIP_MEMORY_SCOPE_AGENT);
      if (((unsigned)(v1 >> 32) == ftag) & ((unsigned)(v2 >> 32) == ftag)) break;
      __builtin_amdgcn_s_sleep(1);
    }
    union { unsigned u; float f; } m1, m2;
    m1.u = (unsigned)v1; m2.u = (unsigned)v2;
    memQ[t * 2] = m1.f;
    memQ[t * 2 + 1] = m2.f;
  }
  __syncthreads();

  if (g == 0 && t < 128) {
    *(float4*)&memfinal[(size_t)seqP * 512 + t * 4] = *(float4*)&memP[t * 4];
    *(float4*)&memfinal[(size_t)seqQ * 512 + t * 4] = *(float4*)&memQ[t * 4];
  }
}

// ---------------- output GEMV ----------------

__global__ __launch_bounds__(256)
void out_gemv_kernel(const float* __restrict__ memf, const float* __restrict__ Wo,
                     const float* __restrict__ bo, float* __restrict__ out) {
  int gid = blockIdx.x * 256 + threadIdx.x;   // 4096 total
  int b = gid >> 9, d = gid & 511;
  const float* mb = memf + (size_t)b * 512;
  float acc = bo[d];
#pragma unroll 8
  for (int k = 0; k < 512; ++k) acc += mb[k] * Wo[(size_t)k * 512 + d];
  out[gid] = acc;
}

// ---------------- launch ----------------

extern "C" void kernel_launch(void* const* d_in, const int* in_sizes, int n_in,
                              void* d_out, int out_size, void* d_ws, size_t ws_size,
                              hipStream_t stream) {
  const float* x   = (const float*)d_in[0];
  const float* Wq  = (const float*)d_in[1];
  const float* bq  = (const float*)d_in[2];
  const float* Wk  = (const float*)d_in[3];
  const float* bk  = (const float*)d_in[4];
  const float* W1  = (const float*)d_in[5];
  const float* b1  = (const float*)d_in[6];
  const float* W2  = (const float*)d_in[7];
  const float* b2  = (const float*)d_in[8];
  const float* lng = (const float*)d_in[9];
  const float* lnb = (const float*)d_in[10];
  const float* Wt1 = (const float*)d_in[11];
  const float* bt1 = (const float*)d_in[12];
  const float* Wt2 = (const float*)d_in[13];
  const float* bt2 = (const float*)d_in[14];
  const float* Wo  = (const float*)d_in[15];
  const float* bo  = (const float*)d_in[16];
  float* out = (float*)d_out;

  char* ws = (char*)d_ws;
  size_t off = 0;
  auto alloc = [&](size_t bytes) -> void* {
    void* p = ws + off;
    off += (bytes + 255) & ~(size_t)255;
    return p;
  };
  float* qk             = (float*)alloc(8ull * 2048 * 64 * 4);
  int* idxb             = (int*)alloc(8ull * 2048 * 4 * 4);
  float* gathf          = (float*)alloc(16384ull * 512 * 4);
  unsigned short* gathb = (unsigned short*)alloc(16384ull * 512 * 2);
  unsigned short* h1b   = (unsigned short*)alloc(16384ull * 1024 * 2);
  float* ypre           = (float*)alloc(16384ull * 512 * 4);
  unsigned short* yb    = (unsigned short*)alloc(16384ull * 512 * 2);
  float* xpart          = (float*)alloc(16384ull * 1024 * 4);
  unsigned short* w1t   = (unsigned short*)alloc(1024ull * 512 * 2);
  unsigned short* w2t   = (unsigned short*)alloc(512ull * 1024 * 2);
  unsigned short* wt1t  = (unsigned short*)alloc(1024ull * 512 * 2);
  float* wt2t           = (float*)alloc(512ull * 1024 * 4);      // Wt2^T fp32
  float* wqkb           = (float*)alloc(512ull * 64 * 4);
  ull* guT              = (ull*)alloc(2ull * 8 * 1024 * 8);      // 128 KB
  ull* memT             = (ull*)alloc(2ull * 8 * 512 * 8);       // 64 KB
  float* memf           = (float*)alloc(8ull * 512 * 4);
  if (off > ws_size) return;  // workspace too small -> visible bench failure

  wqk_kernel<<<128, 256, 0, stream>>>(Wq, Wk, wqkb);
  transpose_bf16_kernel<<<dim3(16, 32), 256, 0, stream>>>(W1, w1t, 512, 1024);
  transpose_bf16_kernel<<<dim3(32, 16), 256, 0, stream>>>(W2, w2t, 1024, 512);
  transpose_bf16_kernel<<<dim3(16, 32), 256, 0, stream>>>(Wt1, wt1t, 512, 1024);
  transpose_f32_kernel<<<dim3(32, 16), 256, 0, stream>>>(Wt2, wt2t, 1024, 512);

  qk_kernel<<<1024, 256, 0, stream>>>(x, wqkb, bq, bk, qk);
  topk_kernel<<<1024, 256, 0, stream>>>(qk, idxb);
  gather_kernel<<<16384, 128, 0, stream>>>(x, idxb, gathf, gathb);

  gemm_bf16_k<0><<<dim3(128, 8), 256, 0, stream>>>(gathb, w1t, b1, nullptr, h1b,
                                                   16384, 1024, 512);
  gemm_bf16_k<1><<<dim3(128, 4), 256, 0, stream>>>(h1b, w2t, b2, gathf, ypre,
                                                   16384, 512, 1024);
  ln_kernel<<<16384, 128, 0, stream>>>(ypre, lng, lnb, yb);
  gemm_bf16_k<2><<<dim3(128, 8), 256, 0, stream>>>(yb, wt1t, bt1, nullptr, xpart,
                                                   16384, 1024, 512);

  system2_kernel<<<128, 256, 0, stream>>>(Wt1, wt2t, bt2, xpart, guT, memT,
                                          memf);
  out_gemv_kernel<<<16, 256, 0, stream>>>(memf, Wo, bo, out);
}

// Round 7
// 8857.682 us; speedup vs baseline: 2.8155x; 1.0694x over previous
//
#include <hip/hip_runtime.h>
#include <math.h>
#include <stdint.h>

// ---------------------------------------------------------------------------
// InvertedCognitionModel: B=8, T=2048, D=512, KQ=32, K=4
//   router (fp32 sim + top4, fused) -> gather-mean -> FFN+LN (bf16 MFMA)
//   -> serial gated memory scan: 8 teams x 32 WGs (full parallel),
//      gu-broadcast structure, DRAIN-FREE flag-hint + tagged-data protocol
//   -> output GEMV
// ---------------------------------------------------------------------------

using bf16x8 = __attribute__((ext_vector_type(8))) short;
using f32x4v = __attribute__((ext_vector_type(4))) float;
typedef unsigned long long ull;

__device__ inline unsigned short f2b(float f) {
  union { float f; unsigned int u; } v; v.f = f;
  unsigned int r = v.u + 0x7fffu + ((v.u >> 16) & 1u);   // RNE
  return (unsigned short)(r >> 16);
}

__device__ inline float gelu_f(float x) {
  return 0.5f * x * (1.0f + erff(x * 0.70710678118654752f));
}

// sorted-descending top-4 insert, tie-break lower index first
__device__ inline void ins4(float v, int i,
                            float& v0, int& i0, float& v1, int& i1,
                            float& v2, int& i2, float& v3, int& i3) {
  bool b0 = (v > v0) || (v == v0 && i < i0);
  bool b1 = (v > v1) || (v == v1 && i < i1);
  bool b2 = (v > v2) || (v == v2 && i < i2);
  bool b3 = (v > v3) || (v == v3 && i < i3);
  float nv3 = b2 ? v2 : (b3 ? v : v3); int ni3 = b2 ? i2 : (b3 ? i : i3);
  float nv2 = b1 ? v1 : (b2 ? v : v2); int ni2 = b1 ? i1 : (b2 ? i : i2);
  float nv1 = b0 ? v0 : (b1 ? v : v1); int ni1 = b0 ? i0 : (b1 ? i : i1);
  float nv0 = b0 ? v  : v0;            int ni0 = b0 ? i  : i0;
  v0=nv0; i0=ni0; v1=nv1; i1=ni1; v2=nv2; i2=ni2; v3=nv3; i3=ni3;
}

// ---------------- prep kernels ----------------

__global__ __launch_bounds__(256)
void wqk_kernel(const float* __restrict__ Wq, const float* __restrict__ Wk,
                float* __restrict__ wqk) {
  int id = blockIdx.x * 256 + threadIdx.x;        // < 512*64
  int d = id >> 6, c = id & 63;
  wqk[id] = (c < 32) ? Wq[d * 32 + c] : Wk[d * 32 + (c - 32)];
}

// dst[n][k] = bf16(src[k][n]); src is [>=K x N] row-major, dst [N x K]
__global__ __launch_bounds__(256)
void transpose_bf16_kernel(const float* __restrict__ src,
                           unsigned short* __restrict__ dst, int K, int N) {
  __shared__ float tile[32][33];
  int bk = blockIdx.x << 5, bn = blockIdx.y << 5;
  int c = threadIdx.x & 31, r8 = threadIdx.x >> 5;
  for (int r = r8; r < 32; r += 8) tile[r][c] = src[(size_t)(bk + r) * N + bn + c];
  __syncthreads();
  for (int r = r8; r < 32; r += 8) dst[(size_t)(bn + r) * K + bk + c] = f2b(tile[c][r]);
}

// dst[n][k] = src[k][n] (fp32), for coalesced LDS staging of Wt2 columns
__global__ __launch_bounds__(256)
void transpose_f32_kernel(const float* __restrict__ src,
                          float* __restrict__ dst, int K, int N) {
  __shared__ float tile[32][33];
  int bk = blockIdx.x << 5, bn = blockIdx.y << 5;
  int c = threadIdx.x & 31, r8 = threadIdx.x >> 5;
  for (int r = r8; r < 32; r += 8) tile[r][c] = src[(size_t)(bk + r) * N + bn + c];
  __syncthreads();
  for (int r = r8; r < 32; r += 8) dst[(size_t)(bn + r) * K + bk + c] = tile[c][r];
}

// ---------------- router ----------------

// q|k projection: qkout[b,t,0:32]=q, [32:64]=k (fp32, biases included)
__global__ __launch_bounds__(256)
void qk_kernel(const float* __restrict__ x, const float* __restrict__ wqk,
               const float* __restrict__ bq, const float* __restrict__ bk,
               float* __restrict__ qkout) {
  __shared__ float xs[16][512];
  int tid = threadIdx.x;
  int b = blockIdx.x >> 7;
  int t0 = (blockIdx.x & 127) << 4;
  const float* xb = x + ((size_t)(b * 2048 + t0)) * 512;
#pragma unroll
  for (int i = 0; i < 8; ++i) {
    int f = i * 256 + tid;
    int r = f >> 7, c4 = f & 127;
    *(float4*)&xs[r][c4 * 4] = *(const float4*)&xb[(size_t)r * 512 + c4 * 4];
  }
  __syncthreads();
  int c = tid & 63, r4 = tid >> 6;
  float a0 = 0.f, a1 = 0.f, a2 = 0.f, a3 = 0.f;
#pragma unroll 4
  for (int d = 0; d < 512; ++d) {
    float w = wqk[d * 64 + c];
    a0 += xs[r4][d] * w;
    a1 += xs[r4 + 4][d] * w;
    a2 += xs[r4 + 8][d] * w;
    a3 += xs[r4 + 12][d] * w;
  }
  float bias = (c < 32) ? bq[c] : bk[c - 32];
  size_t base = ((size_t)(b * 2048 + t0)) * 64 + c;
  qkout[base + (size_t)r4 * 64] = a0 + bias;
  qkout[base + (size_t)(r4 + 4) * 64] = a1 + bias;
  qkout[base + (size_t)(r4 + 8) * 64] = a2 + bias;
  qkout[base + (size_t)(r4 + 12) * 64] = a3 + bias;
}

// fused sim + top-4: block = 16 query rows; never materializes sim
__global__ __launch_bounds__(256)
void topk_kernel(const float* __restrict__ qkb, int* __restrict__ idxout) {
  __shared__ float qs[16][36];
  __shared__ float ks[128][36];
  __shared__ float mv[16][16][4];
  __shared__ int   mi[16][16][4];
  int tid = threadIdx.x;
  int b = blockIdx.x >> 7;
  int t0 = (blockIdx.x & 127) << 4;
  const float* qb = qkb + ((size_t)b * 2048) * 64;
  if (tid < 128) {
    int r = tid >> 3, c4 = tid & 7;
    *(float4*)&qs[r][c4 * 4] = *(const float4*)&qb[(size_t)(t0 + r) * 64 + c4 * 4];
  }
  __syncthreads();
  int tl = tid >> 4, sl = tid & 15;
  float qv[32];
#pragma unroll
  for (int kk = 0; kk < 32; ++kk) qv[kk] = qs[tl][kk];
  float v0 = -INFINITY, v1 = -INFINITY, v2 = -INFINITY, v3 = -INFINITY;
  int i0 = 0x7fffffff, i1 = 0x7fffffff, i2 = 0x7fffffff, i3 = 0x7fffffff;
  for (int s0 = 0; s0 < 2048; s0 += 128) {
    __syncthreads();
#pragma unroll
    for (int p = 0; p < 4; ++p) {
      int f = p * 256 + tid;
      int r = f >> 3, c4 = f & 7;
      *(float4*)&ks[r][c4 * 4] =
          *(const float4*)&qb[(size_t)(s0 + r) * 64 + 32 + c4 * 4];
    }
    __syncthreads();
#pragma unroll
    for (int j = 0; j < 8; ++j) {
      int srow = j * 16 + sl;
      float accv = 0.f;
#pragma unroll
      for (int k4 = 0; k4 < 8; ++k4) {
        float4 kv = *(const float4*)&ks[srow][k4 * 4];
        accv += qv[k4 * 4 + 0] * kv.x + qv[k4 * 4 + 1] * kv.y +
                qv[k4 * 4 + 2] * kv.z + qv[k4 * 4 + 3] * kv.w;
      }
      ins4(accv, s0 + srow, v0, i0, v1, i1, v2, i2, v3, i3);
    }
  }
  mv[tl][sl][0] = v0; mv[tl][sl][1] = v1; mv[tl][sl][2] = v2; mv[tl][sl][3] = v3;
  mi[tl][sl][0] = i0; mi[tl][sl][1] = i1; mi[tl][sl][2] = i2; mi[tl][sl][3] = i3;
  __syncthreads();
  if (tid < 16) {
    float w0 = -INFINITY, w1 = -INFINITY, w2 = -INFINITY, w3 = -INFINITY;
    int a0 = 0x7fffffff, a1 = 0x7fffffff, a2 = 0x7fffffff, a3 = 0x7fffffff;
    for (int ss = 0; ss < 16; ++ss)
#pragma unroll
      for (int q = 0; q < 4; ++q)
        ins4(mv[tid][ss][q], mi[tid][ss][q], w0, a0, w1, a1, w2, a2, w3, a3);
    int4 o; o.x = a0; o.y = a1; o.z = a2; o.w = a3;
    *(int4*)&idxout[((size_t)(b * 2048 + t0 + tid)) * 4] = o;
  }
}

__global__ __launch_bounds__(128)
void gather_kernel(const float* __restrict__ x, const int* __restrict__ idx,
                   float* __restrict__ gf, unsigned short* __restrict__ gb) {
  int bt = blockIdx.x;
  int b = bt >> 11;
  const int4 iv = *(const int4*)&idx[(size_t)bt * 4];
  int tid = threadIdx.x;
  const float* xb = x + ((size_t)b * 2048) * 512;
  float4 p0 = *(const float4*)&xb[(size_t)iv.x * 512 + tid * 4];
  float4 p1 = *(const float4*)&xb[(size_t)iv.y * 512 + tid * 4];
  float4 p2 = *(const float4*)&xb[(size_t)iv.z * 512 + tid * 4];
  float4 p3 = *(const float4*)&xb[(size_t)iv.w * 512 + tid * 4];
  float4 m;
  m.x = (p0.x + p1.x + p2.x + p3.x) * 0.25f;
  m.y = (p0.y + p1.y + p2.y + p3.y) * 0.25f;
  m.z = (p0.z + p1.z + p2.z + p3.z) * 0.25f;
  m.w = (p0.w + p1.w + p2.w + p3.w) * 0.25f;
  *(float4*)&gf[(size_t)bt * 512 + tid * 4] = m;
  ushort4 u; u.x = f2b(m.x); u.y = f2b(m.y); u.z = f2b(m.z); u.w = f2b(m.w);
  *(ushort4*)&gb[(size_t)bt * 512 + tid * 4] = u;
}

// ---------------- MFMA GEMM: C = A[MxK] * Bt[NxK]^T (+bias, epilogues) ------
// MODE 0: out bf16 = gelu(acc+bias)   MODE 1: out f32 = acc+bias+resid
// MODE 2: out f32 = acc+bias

template <int MODE>
__global__ __launch_bounds__(256, 2)
void gemm_bf16_k(const unsigned short* __restrict__ A,
                 const unsigned short* __restrict__ Bt,
                 const float* __restrict__ bias,
                 const float* __restrict__ resid,
                 void* __restrict__ outp, int M, int N, int K) {
  __shared__ unsigned short sA[128 * 32];
  __shared__ unsigned short sB[128 * 32];
  const int tid = threadIdx.x;
  const int lane = tid & 63, wave = tid >> 6;
  const int m0 = blockIdx.x * 128, n0 = blockIdx.y * 128;
  const int col16 = lane & 15, quad = lane >> 4;
  const int wm = wave >> 1, wn = wave & 1;
  f32x4v acc[4][4];
#pragma unroll
  for (int i = 0; i < 4; ++i)
#pragma unroll
    for (int j = 0; j < 4; ++j) {
      f32x4v z = {0.f, 0.f, 0.f, 0.f};
      acc[i][j] = z;
    }
  const int nkt = K >> 5;
  for (int kt = 0; kt < nkt; ++kt) {
    const int k0 = kt << 5;
#pragma unroll
    for (int p = 0; p < 2; ++p) {
      int f = p * 256 + tid;
      int row = f >> 2, q4 = f & 3;
      *(uint4*)&sA[row * 32 + q4 * 8] =
          *(const uint4*)(A + (size_t)(m0 + row) * K + k0 + q4 * 8);
      *(uint4*)&sB[row * 32 + q4 * 8] =
          *(const uint4*)(Bt + (size_t)(n0 + row) * K + k0 + q4 * 8);
    }
    __syncthreads();
    bf16x8 af[4], bfr[4];
#pragma unroll
    for (int i = 0; i < 4; ++i)
      af[i] = *(const bf16x8*)&sA[(wm * 64 + i * 16 + col16) * 32 + quad * 8];
#pragma unroll
    for (int j = 0; j < 4; ++j)
      bfr[j] = *(const bf16x8*)&sB[(wn * 64 + j * 16 + col16) * 32 + quad * 8];
#pragma unroll
    for (int i = 0; i < 4; ++i)
#pragma unroll
      for (int j = 0; j < 4; ++j)
        acc[i][j] = __builtin_amdgcn_mfma_f32_16x16x32_bf16(af[i], bfr[j],
                                                            acc[i][j], 0, 0, 0);
    __syncthreads();
  }
  float* outf = (float*)outp;
  unsigned short* outb = (unsigned short*)outp;
#pragma unroll
  for (int i = 0; i < 4; ++i)
#pragma unroll
    for (int j = 0; j < 4; ++j) {
      int col = n0 + wn * 64 + j * 16 + col16;
      float bs = bias[col];
#pragma unroll
      for (int r = 0; r < 4; ++r) {
        int row = m0 + wm * 64 + i * 16 + quad * 4 + r;
        float v = acc[i][j][r] + bs;
        if (MODE == 0) {
          outb[(size_t)row * N + col] = f2b(gelu_f(v));
        } else if (MODE == 1) {
          outf[(size_t)row * N + col] = v + resid[(size_t)row * N + col];
        } else {
          outf[(size_t)row * N + col] = v;
        }
      }
    }
}

// ---------------- LayerNorm (row-wise, fp32 -> bf16) ----------------

__global__ __launch_bounds__(128)
void ln_kernel(const float* __restrict__ ypre, const float* __restrict__ lg,
               const float* __restrict__ lb, unsigned short* __restrict__ yb) {
  int row = blockIdx.x, tid = threadIdx.x;
  float4 v = *(const float4*)&ypre[(size_t)row * 512 + tid * 4];
  float s = v.x + v.y + v.z + v.w;
  float sq = v.x * v.x + v.y * v.y + v.z * v.z + v.w * v.w;
#pragma unroll
  for (int off = 1; off < 64; off <<= 1) {
    s += __shfl_xor(s, off, 64);
    sq += __shfl_xor(sq, off, 64);
  }
  __shared__ float red[4];
  if ((tid & 63) == 0) { red[(tid >> 6) * 2] = s; red[(tid >> 6) * 2 + 1] = sq; }
  __syncthreads();
  float S = red[0] + red[2], SQ = red[1] + red[3];
  float mu = S * (1.f / 512.f);
  float var = SQ * (1.f / 512.f) - mu * mu;
  float rstd = rsqrtf(var + 1e-5f);
  float4 g4 = *(const float4*)&lg[tid * 4];
  float4 b4 = *(const float4*)&lb[tid * 4];
  ushort4 u;
  u.x = f2b((v.x - mu) * rstd * g4.x + b4.x);
  u.y = f2b((v.y - mu) * rstd * g4.y + b4.y);
  u.z = f2b((v.z - mu) * rstd * g4.z + b4.z);
  u.w = f2b((v.w - mu) * rstd * g4.w + b4.w);
  *(ushort4*)&yb[(size_t)row * 512 + tid * 4] = u;
}

// ---------------- System2: persistent serial scan --------------------------
// 8 teams x 32 WGs x 256 thr; blockIdx = g*8 + team (champion layout).
// WG g owns u-cols [g*32,g*32+32) and mem-cols [g*16,g*16+16).
// gu-BROADCAST structure (R2, verified): round A = 1024 words/team (gu),
// round B = 512 words/team (mem).
//
// PROTOCOL v7 (drain-free flag-hint + tagged data) — the R0 vs R2/R6 lesson:
//  * R0 champion (flags + vmcnt(0) drain): 3.89us/step. Chain = data stores
//    -> ~900cy drain (order data-before-flag) -> flag flight -> low-traffic
//    flag poll -> data loads.
//  * R2/R6 (per-word tagged polls by all 256 threads): 4.25us/step and fat
//    tails — the 256-thr x 6-word poll flood inflates LLC RTT.
//  * v7 = champion chain MINUS the drain: data words carry tags
//    (tag<<32)|float_bits (8B single-copy atomic), so the producer fires the
//    flag IMMEDIATELY (no vmcnt drain) — the flag is only a low-traffic
//    "likely ready" hint; tags are the sole correctness guard. Consumers:
//    champion-style 32-flag poll (t<64, tiny traffic), barrier, ONE bulk
//    tagged load + verify; stragglers (flag won the race to the LLC against
//    some data word — rare) re-poll just their own words.
// Monotone tags vs stale/poison: expected tag s+1 counts up from 1; a slot
// last written at step s-2 holds tag s-1; prev-launch finals are 2047/2048;
// harness poison is 0xAAAAAAAA — no false match. Flags same. Overwrite
// safety as R2: any parity-slot overwrite at s+2 is gated through polls that
// transitively require every WG past the phase that last read the slot.

__global__ __launch_bounds__(256)
void system2_kernel(const float* __restrict__ Wt1, const float* __restrict__ Wt2T,
                    const float* __restrict__ bt2, const float* __restrict__ xpart,
                    ull* __restrict__ guT, ull* __restrict__ memT,
                    int* __restrict__ flagT, float* __restrict__ memfinal) {
  __shared__ float WbT[32 * 516];    // stage1 W [j][k], stride 516 (66048 B)
  __shared__ float W2S[16 * 1028];   // stage2 W [dd][u], stride 1028 (65792 B)
  __shared__ float memS[512];
  __shared__ float guA[1024];
  __shared__ float parts1[256];      // [c][j] = [8][32]
  __shared__ float red2[256];        // [c2][dd] = [16][16]

  const int t = threadIdx.x;
  const int team = blockIdx.x & 7;
  const int g = blockIdx.x >> 3;          // 0..31
  const int ucol0 = g << 5;
  const int mcol0 = g << 4;

  // ---- load weights into LDS (one-time) ----
  for (int idx = t; idx < 32 * 512; idx += 256) {
    int j = idx & 31, k = idx >> 5;
    WbT[j * 516 + k] = Wt1[(size_t)(512 + k) * 1024 + ucol0 + j];
  }
  for (int idx = t; idx < 16 * 1024; idx += 256) {
    int dd = idx >> 10, u = idx & 1023;
    W2S[dd * 1028 + u] = Wt2T[(size_t)(mcol0 + dd) * 1024 + u];
  }
  memS[t] = 0.f;
  memS[t + 256] = 0.f;
  const float bt2r = (t < 16) ? bt2[mcol0 + t] : 0.f;
  __syncthreads();

  const int j = t & 31, c = t >> 5;        // stage1 roles: col j, k-chunk c(8)
  const int dd = t & 15, c2 = t >> 4;      // stage2 roles: col dd, u-chunk c2(16)
  const float* xp = xpart + (size_t)team * 2048 * 1024 + ucol0;
  float xv = (t < 32) ? xp[t] : 0.f;

  for (int s = 0; s < 2048; ++s) {
    const int par = s & 1;
    ull* gub = guT + (size_t)(par * 8 + team) * 1024;
    ull* memb = memT + (size_t)(par * 8 + team) * 512;
    int* flA = flagT + (par * 8 + team) * 128;        // 32 flags (A)
    int* flB = flagT + (par * 8 + team) * 128 + 64;   // 32 flags (B)
    const int tag = s + 1;
    const unsigned utag = (unsigned)tag;
    const ull tagw = ((ull)utag) << 32;

    // xpart prefetch (issued early; consumed at loop end — off critical path)
    float xnext = (t < 32 && s < 2047) ? xp[(size_t)(s + 1) * 1024 + t] : 0.f;

    // ---- stage1: u[ucol0+j] partial over k-chunk c (64 k), float4 LDS ----
    {
      const float* wrow = &WbT[j * 516 + c * 64];
      const float* mrow = &memS[c * 64];
      float p1 = 0.f;
#pragma unroll
      for (int i = 0; i < 64; i += 4) {
        float4 wv = *(const float4*)&wrow[i];
        float4 mv = *(const float4*)&mrow[i];
        p1 += wv.x * mv.x + wv.y * mv.y + wv.z * mv.z + wv.w * mv.w;
      }
      parts1[c * 32 + j] = p1;
    }
    __syncthreads();
    // ---- own 32 gu values: reduce, gelu, tagged store + IMMEDIATE flag ----
    if (t < 32) {
      float u = xv;   // xpart includes xt@Wt1[:512] + bt1
#pragma unroll
      for (int cc = 0; cc < 8; ++cc) u += parts1[cc * 32 + t];
      union { float f; unsigned u; } uv; uv.f = gelu_f(u);
      __hip_atomic_store(&gub[ucol0 + t], tagw | uv.u, __ATOMIC_RELAXED,
                         __HIP_MEMORY_SCOPE_AGENT);
    }
    asm volatile("" ::: "memory");   // compiler order: data stores before flag
    if (t == 0)
      __hip_atomic_store(&flA[g], tag, __ATOMIC_RELAXED,
                         __HIP_MEMORY_SCOPE_AGENT);   // NO drain — tags guard
    // ---- flag-hint poll A (champion-style, low traffic) ----
    if (t < 64) {
      int f = (t < 32) ? 0 : tag;
      const int* fp = &flA[t < 32 ? t : 0];
      while (true) {
        if (t < 32 && f != tag)
          f = __hip_atomic_load(fp, __ATOMIC_RELAXED, __HIP_MEMORY_SCOPE_AGENT);
        if (__ballot(f == tag) == ~0ull) break;
        __builtin_amdgcn_s_sleep(1);
      }
    }
    __syncthreads();
    // ---- bulk tagged load of full gu (4 words/thread) + verify ----
    {
      ull* p = &gub[t * 4];
      ull v0 = __hip_atomic_load(&p[0], __ATOMIC_RELAXED, __HIP_MEMORY_SCOPE_AGENT);
      ull v1 = __hip_atomic_load(&p[1], __ATOMIC_RELAXED, __HIP_MEMORY_SCOPE_AGENT);
      ull v2 = __hip_atomic_load(&p[2], __ATOMIC_RELAXED, __HIP_MEMORY_SCOPE_AGENT);
      ull v3 = __hip_atomic_load(&p[3], __ATOMIC_RELAXED, __HIP_MEMORY_SCOPE_AGENT);
      bool ok = ((unsigned)(v0 >> 32) == utag) & ((unsigned)(v1 >> 32) == utag) &
                ((unsigned)(v2 >> 32) == utag) & ((unsigned)(v3 >> 32) == utag);
      if (!ok) {   // rare straggler: flag beat a data word to the LLC
        for (;;) {
          v0 = __hip_atomic_load(&p[0], __ATOMIC_RELAXED, __HIP_MEMORY_SCOPE_AGENT);
          v1 = __hip_atomic_load(&p[1], __ATOMIC_RELAXED, __HIP_MEMORY_SCOPE_AGENT);
          v2 = __hip_atomic_load(&p[2], __ATOMIC_RELAXED, __HIP_MEMORY_SCOPE_AGENT);
          v3 = __hip_atomic_load(&p[3], __ATOMIC_RELAXED, __HIP_MEMORY_SCOPE_AGENT);
          ok = ((unsigned)(v0 >> 32) == utag) & ((unsigned)(v1 >> 32) == utag) &
               ((unsigned)(v2 >> 32) == utag) & ((unsigned)(v3 >> 32) == utag);
          if (ok) break;
          __builtin_amdgcn_s_sleep(1);
        }
      }
      union { unsigned u; float f; } a0, a1, a2, a3;
      a0.u = (unsigned)v0; a1.u = (unsigned)v1;
      a2.u = (unsigned)v2; a3.u = (unsigned)v3;
      guA[t * 4 + 0] = a0.f;
      guA[t * 4 + 1] = a1.f;
      guA[t * 4 + 2] = a2.f;
      guA[t * 4 + 3] = a3.f;
    }
    __syncthreads();

    // ---- stage2: full prop for own col (mcol0+dd), u-chunk c2 (64 u) ----
    {
      const float* wrow = &W2S[dd * 1028 + c2 * 64];
      const float* grow = &guA[c2 * 64];
      float p2 = 0.f;
#pragma unroll
      for (int i = 0; i < 64; i += 4) {
        float4 wv = *(const float4*)&wrow[i];
        float4 gv = *(const float4*)&grow[i];
        p2 += wv.x * gv.x + wv.y * gv.y + wv.z * gv.z + wv.w * gv.w;
      }
      red2[c2 * 16 + dd] = p2;
    }
    __syncthreads();
    // ---- own 16 mem-cols: reduce, gate, tagged store + IMMEDIATE flag ----
    if (t < 16) {
      float prop = bt2r;
#pragma unroll
      for (int cc = 0; cc < 16; ++cc) prop += red2[cc * 16 + t];
      float gate = 1.f / (1.f + __expf(-prop));
      float mnew = memS[mcol0 + t] * (1.f - gate) + prop * gate;
      union { float f; unsigned u; } mv; mv.f = mnew;
      __hip_atomic_store(&memb[mcol0 + t], tagw | mv.u, __ATOMIC_RELAXED,
                         __HIP_MEMORY_SCOPE_AGENT);
    }
    asm volatile("" ::: "memory");
    if (t == 0)
      __hip_atomic_store(&flB[g], tag, __ATOMIC_RELAXED,
                         __HIP_MEMORY_SCOPE_AGENT);
    // ---- flag-hint poll B ----
    if (t < 64) {
      int f = (t < 32) ? 0 : tag;
      const int* fp = &flB[t < 32 ? t : 0];
      while (true) {
        if (t < 32 && f != tag)
          f = __hip_atomic_load(fp, __ATOMIC_RELAXED, __HIP_MEMORY_SCOPE_AGENT);
        if (__ballot(f == tag) == ~0ull) break;
        __builtin_amdgcn_s_sleep(1);
      }
    }
    __syncthreads();
    // ---- bulk tagged load of full mem (2 words/thread) + verify ----
    {
      ull* q = &memb[t * 2];
      ull v1 = __hip_atomic_load(&q[0], __ATOMIC_RELAXED, __HIP_MEMORY_SCOPE_AGENT);
      ull v2 = __hip_atomic_load(&q[1], __ATOMIC_RELAXED, __HIP_MEMORY_SCOPE_AGENT);
      if (((unsigned)(v1 >> 32) != utag) | ((unsigned)(v2 >> 32) != utag)) {
        for (;;) {
          v1 = __hip_atomic_load(&q[0], __ATOMIC_RELAXED, __HIP_MEMORY_SCOPE_AGENT);
          v2 = __hip_atomic_load(&q[1], __ATOMIC_RELAXED, __HIP_MEMORY_SCOPE_AGENT);
          if (((unsigned)(v1 >> 32) == utag) & ((unsigned)(v2 >> 32) == utag)) break;
          __builtin_amdgcn_s_sleep(1);
        }
      }
      union { unsigned u; float f; } m1, m2;
      m1.u = (unsigned)v1; m2.u = (unsigned)v2;
      memS[t * 2] = m1.f;
      memS[t * 2 + 1] = m2.f;
    }
    xv = xnext;
    __syncthreads();
  }

  if (g == 0 && t < 128)
    *(float4*)&memfinal[(size_t)team * 512 + t * 4] = *(float4*)&memS[t * 4];
}

// ---------------- output GEMV ----------------

__global__ __launch_bounds__(256)
void out_gemv_kernel(const float* __restrict__ memf, const float* __restrict__ Wo,
                     const float* __restrict__ bo, float* __restrict__ out) {
  int gid = blockIdx.x * 256 + threadIdx.x;   // 4096 total
  int b = gid >> 9, d = gid & 511;
  const float* mb = memf + (size_t)b * 512;
  float acc = bo[d];
#pragma unroll 8
  for (int k = 0; k < 512; ++k) acc += mb[k] * Wo[(size_t)k * 512 + d];
  out[gid] = acc;
}

// ---------------- launch ----------------

extern "C" void kernel_launch(void* const* d_in, const int* in_sizes, int n_in,
                              void* d_out, int out_size, void* d_ws, size_t ws_size,
                              hipStream_t stream) {
  const float* x   = (const float*)d_in[0];
  const float* Wq  = (const float*)d_in[1];
  const float* bq  = (const float*)d_in[2];
  const float* Wk  = (const float*)d_in[3];
  const float* bk  = (const float*)d_in[4];
  const float* W1  = (const float*)d_in[5];
  const float* b1  = (const float*)d_in[6];
  const float* W2  = (const float*)d_in[7];
  const float* b2  = (const float*)d_in[8];
  const float* lng = (const float*)d_in[9];
  const float* lnb = (const float*)d_in[10];
  const float* Wt1 = (const float*)d_in[11];
  const float* bt1 = (const float*)d_in[12];
  const float* Wt2 = (const float*)d_in[13];
  const float* bt2 = (const float*)d_in[14];
  const float* Wo  = (const float*)d_in[15];
  const float* bo  = (const float*)d_in[16];
  float* out = (float*)d_out;

  char* ws = (char*)d_ws;
  size_t off = 0;
  auto alloc = [&](size_t bytes) -> void* {
    void* p = ws + off;
    off += (bytes + 255) & ~(size_t)255;
    return p;
  };
  float* qk             = (float*)alloc(8ull * 2048 * 64 * 4);
  int* idxb             = (int*)alloc(8ull * 2048 * 4 * 4);
  float* gathf          = (float*)alloc(16384ull * 512 * 4);
  unsigned short* gathb = (unsigned short*)alloc(16384ull * 512 * 2);
  unsigned short* h1b   = (unsigned short*)alloc(16384ull * 1024 * 2);
  float* ypre           = (float*)alloc(16384ull * 512 * 4);
  unsigned short* yb    = (unsigned short*)alloc(16384ull * 512 * 2);
  float* xpart          = (float*)alloc(16384ull * 1024 * 4);
  unsigned short* w1t   = (unsigned short*)alloc(1024ull * 512 * 2);
  unsigned short* w2t   = (unsigned short*)alloc(512ull * 1024 * 2);
  unsigned short* wt1t  = (unsigned short*)alloc(1024ull * 512 * 2);
  float* wt2t           = (float*)alloc(512ull * 1024 * 4);      // Wt2^T fp32
  float* wqkb           = (float*)alloc(512ull * 64 * 4);
  ull* guT              = (ull*)alloc(2ull * 8 * 1024 * 8);      // 128 KB
  ull* memT             = (ull*)alloc(2ull * 8 * 512 * 8);       // 64 KB
  int* flagT            = (int*)alloc(2ull * 8 * 128 * 4);       // 8 KB
  float* memf           = (float*)alloc(8ull * 512 * 4);
  if (off > ws_size) return;  // workspace too small -> visible bench failure

  wqk_kernel<<<128, 256, 0, stream>>>(Wq, Wk, wqkb);
  transpose_bf16_kernel<<<dim3(16, 32), 256, 0, stream>>>(W1, w1t, 512, 1024);
  transpose_bf16_kernel<<<dim3(32, 16), 256, 0, stream>>>(W2, w2t, 1024, 512);
  transpose_bf16_kernel<<<dim3(16, 32), 256, 0, stream>>>(Wt1, wt1t, 512, 1024);
  transpose_f32_kernel<<<dim3(32, 16), 256, 0, stream>>>(Wt2, wt2t, 1024, 512);

  qk_kernel<<<1024, 256, 0, stream>>>(x, wqkb, bq, bk, qk);
  topk_kernel<<<1024, 256, 0, stream>>>(qk, idxb);
  gather_kernel<<<16384, 128, 0, stream>>>(x, idxb, gathf, gathb);

  gemm_bf16_k<0><<<dim3(128, 8), 256, 0, stream>>>(gathb, w1t, b1, nullptr, h1b,
                                                   16384, 1024, 512);
  gemm_bf16_k<1><<<dim3(128, 4), 256, 0, stream>>>(h1b, w2t, b2, gathf, ypre,
                                                   16384, 512, 1024);
  ln_kernel<<<16384, 128, 0, stream>>>(ypre, lng, lnb, yb);
  gemm_bf16_k<2><<<dim3(128, 8), 256, 0, stream>>>(yb, wt1t, bt1, nullptr, xpart,
                                                   16384, 1024, 512);

  system2_kernel<<<256, 256, 0, stream>>>(Wt1, wt2t, bt2, xpart, guT, memT,
                                          flagT, memf);
  out_gemv_kernel<<<16, 256, 0, stream>>>(memf, Wo, bo, out);
}